// Round 12
// baseline (646.979 us; speedup 1.0000x reference)
//
#include <hip/hip_runtime.h>
#include <hip/hip_bf16.h>

using bf16 = __hip_bfloat16;
typedef __bf16 bf16x8 __attribute__((ext_vector_type(8)));
typedef float f32x4 __attribute__((ext_vector_type(4)));

constexpr int DD   = 128;
constexpr int NACT = 8000;
constexpr int NN   = 40000;
constexpr int E1   = 65536;
constexpr int EE   = 3 * E1;

#define BM 128

__device__ __forceinline__ void gload16(const void* g, void* l) {
  __builtin_amdgcn_global_load_lds((const __attribute__((address_space(1))) void*)g,
                                   (__attribute__((address_space(3))) void*)l, 16, 0, 0);
}

__device__ __forceinline__ int edge_dst(int e, const int* e0, const int* e1, const int* e2) {
  int ty = e >> 16, idx = e & 65535;
  const int* ep = (ty == 0) ? e0 : ((ty == 1) ? e1 : e2);
  return ep[E1 + idx];
}
__device__ __forceinline__ int edge_src(int e, const int* e0, const int* e1, const int* e2) {
  int ty = e >> 16, idx = e & 65535;
  const int* ep = (ty == 0) ? e0 : ((ty == 1) ? e1 : e2);
  return ep[idx];
}

// plain pitched LDS mfma step (msg GEMM)
__device__ __forceinline__ void mfma_step(const bf16* A0, int lda, const bf16* B0, int ldb,
                                          f32x4 acc[4][4], int wm, int wn, int lane) {
  const int lr = lane & 15;
  const int lk = (lane >> 4) * 8;
  bf16x8 a[4], b[4];
#pragma unroll
  for (int i = 0; i < 4; i++)
    a[i] = *(const bf16x8*)(A0 + (size_t)(wm * 64 + i * 16 + lr) * lda + lk);
#pragma unroll
  for (int j = 0; j < 4; j++)
    b[j] = *(const bf16x8*)(B0 + (size_t)(wn * 64 + j * 16 + lr) * ldb + lk);
#pragma unroll
  for (int i = 0; i < 4; i++)
#pragma unroll
    for (int j = 0; j < 4; j++)
      acc[i][j] = __builtin_amdgcn_mfma_f32_16x16x32_bf16(a[i], b[j], acc[i][j], 0, 0, 0);
}

// both operands in unpadded [128][32] gload_lds buffers with chunk swizzle
__device__ __forceinline__ void mfma_swz(const bf16* A0, const bf16* B0,
                                         f32x4 acc[4][4], int wm, int wn, int lane) {
  const int lr = lane & 15;
  const int g  = lane >> 4;
  const int sw = (g ^ ((lr >> 1) & 3)) * 8;
  bf16x8 a[4], b[4];
#pragma unroll
  for (int i = 0; i < 4; i++)
    a[i] = *(const bf16x8*)(A0 + (wm * 64 + i * 16 + lr) * 32 + sw);
#pragma unroll
  for (int j = 0; j < 4; j++)
    b[j] = *(const bf16x8*)(B0 + (wn * 64 + j * 16 + lr) * 32 + sw);
#pragma unroll
  for (int i = 0; i < 4; i++)
#pragma unroll
    for (int j = 0; j < 4; j++)
      acc[i][j] = __builtin_amdgcn_mfma_f32_16x16x32_bf16(a[i], b[j], acc[i][j], 0, 0, 0);
}

// A from pitched mem_s, B from swizzled gload buffer
__device__ __forceinline__ void mfma_mixed(const bf16* Am, int lda, const bf16* B0,
                                           f32x4 acc[4][4], int wm, int wn, int lane) {
  const int lr = lane & 15;
  const int g  = lane >> 4;
  const int sw = (g ^ ((lr >> 1) & 3)) * 8;
  bf16x8 a[4], b[4];
#pragma unroll
  for (int i = 0; i < 4; i++)
    a[i] = *(const bf16x8*)(Am + (size_t)(wm * 64 + i * 16 + lr) * lda + g * 8);
#pragma unroll
  for (int j = 0; j < 4; j++)
    b[j] = *(const bf16x8*)(B0 + (wn * 64 + j * 16 + lr) * 32 + sw);
#pragma unroll
  for (int i = 0; i < 4; i++)
#pragma unroll
    for (int j = 0; j < 4; j++)
      acc[i][j] = __builtin_amdgcn_mfma_f32_16x16x32_bf16(a[i], b[j], acc[i][j], 0, 0, 0);
}

__device__ __forceinline__ void row_ln_stats(const f32x4 acc[4][4], float* red_s,
                                             float* red_q, int wm, int wn, int lane) {
  const int lr = lane & 15, lg = lane >> 4;
#pragma unroll
  for (int i = 0; i < 4; i++) {
#pragma unroll
    for (int q = 0; q < 4; q++) {
      float s = acc[i][0][q] + acc[i][1][q] + acc[i][2][q] + acc[i][3][q];
      float t = acc[i][0][q] * acc[i][0][q] + acc[i][1][q] * acc[i][1][q]
              + acc[i][2][q] * acc[i][2][q] + acc[i][3][q] * acc[i][3][q];
#pragma unroll
      for (int off = 1; off < 16; off <<= 1) {
        s += __shfl_xor(s, off);
        t += __shfl_xor(t, off);
      }
      if (lr == 0) {
        int row = wm * 64 + i * 16 + lg * 4 + q;
        red_s[wn * 128 + row] = s;
        red_q[wn * 128 + row] = t;
      }
    }
  }
}

// ======= PS precompute: for y=l*2+part, out = x0 @ Wmp_l[:, part*128:(part+1)*128]^T =======
__global__ __launch_bounds__(256, 3) void k_ps(
    const bf16* __restrict__ A, const bf16* __restrict__ Wmp,
    bf16* __restrict__ ps01, bf16* __restrict__ ps2, int M)
{
  __shared__ __align__(16) char smem[36864];
  bf16* const stg = (bf16*)smem;

  const int tid = threadIdx.x, lane = tid & 63, w = tid >> 6;
  const int wm = w >> 1, wn = w & 1;
  const int bm0 = blockIdx.x * BM;
  const int y = blockIdx.y, l = y >> 1, part = y & 1;
  const int swzE = ((lane & 3) ^ ((lane >> 3) & 3)) * 8;

  const bf16* pA[2];
  const bf16* pB[2];
#pragma unroll
  for (int r = 0; r < 2; r++) {
    int ra = bm0 + r * 64 + w * 16 + (lane >> 2);
    if (ra > M - 1) ra = M - 1;
    pA[r] = A + (size_t)ra * DD + swzE;
    int rb = r * 64 + w * 16 + (lane >> 2);
    pB[r] = Wmp + (size_t)l * 49152 + (size_t)rb * 384 + part * 128 + swzE;
  }
  auto STAGE = [&](int kb, int buf) {
#pragma unroll
    for (int r = 0; r < 2; r++) {
      gload16(pA[r] + kb * 32, smem + buf * 8192 + r * 4096 + w * 1024);
      gload16(pB[r] + kb * 32, smem + 16384 + buf * 8192 + r * 4096 + w * 1024);
    }
  };

  f32x4 acc[4][4] = {};
  STAGE(0, 0);
  __syncthreads();
  int buf = 0;
#pragma unroll 1
  for (int kb = 0; kb < 4; kb++) {
    if (kb + 1 < 4) STAGE(kb + 1, buf ^ 1);
    mfma_swz((const bf16*)(smem + buf * 8192), (const bf16*)(smem + 16384 + buf * 8192),
             acc, wm, wn, lane);
    __syncthreads();
    buf ^= 1;
  }

  const int lr = lane & 15, lg = lane >> 4;
  const int colb = wn * 64 + lr;
  const int rowb = wm * 64 + lg * 4;
#pragma unroll
  for (int i = 0; i < 4; i++)
#pragma unroll
    for (int q = 0; q < 4; q++) {
      int row = rowb + i * 16 + q;
#pragma unroll
      for (int j = 0; j < 4; j++)
        stg[row * 136 + colb + j * 16] = __float2bfloat16(acc[i][j][q]);
    }
  __syncthreads();
  bf16* ob;
  int ldps, coff;
  if (l < 2) { ob = ps01; ldps = 512; coff = y * 128; }
  else       { ob = ps2;  ldps = 256; coff = part * 128; }
#pragma unroll
  for (int c = 0; c < 8; c++) {
    int off = c * 2048 + tid * 8;
    int row = off >> 7, col = off & 127;
    int r = bm0 + row;
    if (r < M)
      *(uint4*)(ob + (size_t)r * ldps + coff + col) = *(uint4*)&stg[row * 136 + col];
  }
}

// ================= fused edge-layer kernel (ea-part GEMM + P/S gather-add) =================
// LDS: ring 2x16KB [0,32768) aliased by mem_s [0,34816)=[128][136]
//      Bs2 [34816,43008) ; red [43008,45056) ; idx [45056,46080)
template<int LAST>
__global__ __launch_bounds__(256, 3) void k_fused(
    const bf16* __restrict__ Wmp, const bf16* __restrict__ W2,
    const float* __restrict__ mpb, const float* __restrict__ eub,
    bf16* eah, const bf16* __restrict__ PSd, const bf16* __restrict__ PSs, int ldps,
    const bf16* __restrict__ qh, bf16* vout,
    float* __restrict__ logi, unsigned* __restrict__ nmax,
    const int* __restrict__ e0, const int* __restrict__ e1, const int* __restrict__ e2)
{
  __shared__ __align__(16) char smem[46080];
  bf16* const mem_s = (bf16*)smem;                    // [128][136]
  bf16* const Bs2   = (bf16*)(smem + 34816);          // [128][32]
  float* const red_s = (float*)(smem + 43008);
  float* const red_q = (float*)(smem + 44032);
  int* const sdst = (int*)(smem + 45056);
  int* const ssrc = (int*)(smem + 45568);

  const int tid = threadIdx.x;
  const int bm0 = blockIdx.x * BM;
  const int lane = tid & 63, w = tid >> 6, wm = w >> 1, wn = w & 1;
  const int swzE = ((lane & 3) ^ ((lane >> 3) & 3)) * 8;

  if (tid < 128) sdst[tid] = edge_dst(bm0 + tid, e0, e1, e2);
  else           ssrc[tid - 128] = edge_src(bm0 + tid - 128, e0, e1, e2);
  __syncthreads();
  const int mr0 = w * 16 + (lane >> 2), mr1 = 64 + mr0;
  const bf16* pe0 = eah + (size_t)(bm0 + mr0) * DD + swzE;
  const bf16* pe1 = eah + (size_t)(bm0 + mr1) * DD + swzE;
  const bf16* pBc0 = Wmp + (size_t)mr0 * 384 + 256 + swzE;   // W_c = cols 256:384
  const bf16* pBc1 = Wmp + (size_t)mr1 * 384 + 256 + swzE;
  const bf16* pW20 = W2 + (size_t)mr0 * DD + swzE;
  const bf16* pW21 = W2 + (size_t)mr1 * DD + swzE;

  auto STAGE1 = [&](int kb, int buf) {
    char* base = smem + buf * 16384;
    gload16(pe0 + kb * 32, base + w * 1024);
    gload16(pe1 + kb * 32, base + 4096 + w * 1024);
    gload16(pBc0 + kb * 32, base + 8192 + w * 1024);
    gload16(pBc1 + kb * 32, base + 12288 + w * 1024);
  };

  // ---- GEMM1 (ea part only): K=128, 2-phase, 1 barrier/step ----
  f32x4 acc[4][4] = {};
  STAGE1(0, 0);
  __syncthreads();
  int buf = 0;
#pragma unroll
  for (int kb = 0; kb < 4; kb++) {
    if (kb < 3) STAGE1(kb + 1, buf ^ 1);
    mfma_swz((const bf16*)(smem + buf * 16384), (const bf16*)(smem + buf * 16384 + 8192),
             acc, wm, wn, lane);
    __syncthreads();
    buf ^= 1;
  }

  const int lr = lane & 15, lg = lane >> 4;
  const int colb = wn * 64 + lr;
  const int rowb = wm * 64 + lg * 4;

  // ---- epilogue 1: + bias + P[dst] + S[src], LN + relu -> mem_s ----
#pragma unroll
  for (int j = 0; j < 4; j++) {
    float bj = mpb[colb + j * 16];
#pragma unroll
    for (int i = 0; i < 4; i++)
#pragma unroll
      for (int q = 0; q < 4; q++) acc[i][j][q] += bj;
  }
#pragma unroll
  for (int i = 0; i < 4; i++) {
#pragma unroll
    for (int q = 0; q < 4; q++) {
      int row = rowb + i * 16 + q;
      const bf16* pd = PSd + (size_t)sdst[row] * ldps + colb;
      const bf16* ps = PSs + (size_t)ssrc[row] * ldps + colb;
#pragma unroll
      for (int j = 0; j < 4; j++)
        acc[i][j][q] += __bfloat162float(pd[j * 16]) + __bfloat162float(ps[j * 16]);
    }
  }
  row_ln_stats(acc, red_s, red_q, wm, wn, lane);
  __syncthreads();
#pragma unroll
  for (int i = 0; i < 4; i++) {
#pragma unroll
    for (int q = 0; q < 4; q++) {
      int row = rowb + i * 16 + q;
      float Sm = red_s[row] + red_s[128 + row];
      float Qs = red_q[row] + red_q[128 + row];
      float mu = Sm * 0.0078125f;
      float var = Qs * 0.0078125f - mu * mu;
      float inv = 1.0f / sqrtf(var + 1e-5f);
#pragma unroll
      for (int j = 0; j < 4; j++)
        mem_s[row * 136 + colb + j * 16] =
            __float2bfloat16(fmaxf((acc[i][j][q] - mu) * inv, 0.f));
    }
  }
  // (visibility of mem_s: first barrier inside GEMM2 loop)

  auto GEMM2 = [&](int voff, f32x4 a2[4][4]) {
#pragma unroll 1
    for (int kb = 0; kb < 4; kb++) {
      __syncthreads();
      gload16(pW20 + voff + kb * 32, smem + 34816 + w * 1024);
      gload16(pW21 + voff + kb * 32, smem + 34816 + 4096 + w * 1024);
      __syncthreads();
      mfma_mixed(mem_s + kb * 32, 136, Bs2, a2, wm, wn, lane);
    }
  };
  auto store_tile = [&](bf16* dst) {
#pragma unroll
    for (int c = 0; c < 8; c++) {
      int off = c * 2048 + tid * 8;
      int row = off >> 7, col = off & 127;
      *(uint4*)(dst + (size_t)bm0 * DD + off) = *(uint4*)&mem_s[row * 136 + col];
    }
  };

  if constexpr (LAST == 0) {
    f32x4 acc2[4][4] = {};
    GEMM2(0, acc2);
    // delta = relu(LN(acc2+eub)); ea = LN(ea + delta)
#pragma unroll
    for (int j = 0; j < 4; j++) {
      float bj = eub[colb + j * 16];
#pragma unroll
      for (int i = 0; i < 4; i++)
#pragma unroll
        for (int q = 0; q < 4; q++) acc2[i][j][q] += bj;
    }
    __syncthreads();
    row_ln_stats(acc2, red_s, red_q, wm, wn, lane);
    __syncthreads();
#pragma unroll
    for (int i = 0; i < 4; i++) {
#pragma unroll
      for (int q = 0; q < 4; q++) {
        int row = rowb + i * 16 + q;
        float Sm = red_s[row] + red_s[128 + row];
        float Qs = red_q[row] + red_q[128 + row];
        float mu = Sm * 0.0078125f;
        float var = Qs * 0.0078125f - mu * mu;
        float inv = 1.0f / sqrtf(var + 1e-5f);
        int r = bm0 + row;
#pragma unroll
        for (int j = 0; j < 4; j++) {
          float d = fmaxf((acc2[i][j][q] - mu) * inv, 0.f);
          float eo = __bfloat162float(eah[(size_t)r * DD + colb + j * 16]);
          acc2[i][j][q] = eo + d;
        }
      }
    }
    __syncthreads();
    row_ln_stats(acc2, red_s, red_q, wm, wn, lane);
    __syncthreads();
#pragma unroll
    for (int i = 0; i < 4; i++) {
#pragma unroll
      for (int q = 0; q < 4; q++) {
        int row = rowb + i * 16 + q;
        float Sm = red_s[row] + red_s[128 + row];
        float Qs = red_q[row] + red_q[128 + row];
        float mu = Sm * 0.0078125f;
        float var = Qs * 0.0078125f - mu * mu;
        float inv = 1.0f / sqrtf(var + 1e-5f);
#pragma unroll
        for (int j = 0; j < 4; j++)
          mem_s[row * 136 + colb + j * 16] =
              __float2bfloat16((acc2[i][j][q] - mu) * inv);
      }
    }
    __syncthreads();
    store_tile(eah);
  } else {
    // ---- K = mem @ W_K^T ; logits in-register ----
    f32x4 acc2[4][4] = {};
    GEMM2(0, acc2);
#pragma unroll
    for (int i = 0; i < 4; i++) {
#pragma unroll
      for (int q = 0; q < 4; q++) {
        int row = rowb + i * 16 + q;
        int dst = sdst[row];
#pragma unroll
        for (int j = 0; j < 4; j++) {
          int h = wn * 4 + j;
          float qv = __bfloat162float(qh[(size_t)dst * DD + h * 16 + lr]);
          float p = acc2[i][j][q] * qv;
#pragma unroll
          for (int off = 1; off < 16; off <<= 1) p += __shfl_xor(p, off);
          if (lr == 0) {
            p *= 0.25f;
            int e = bm0 + row;
            logi[(size_t)e * 8 + h] = p;
            unsigned u = __float_as_uint(p);
            u = (u & 0x80000000u) ? ~u : (u | 0x80000000u);
            atomicMax(nmax + (size_t)dst * 8 + h, u);
          }
        }
      }
    }
    // ---- V = mem @ W_V^T ----
    f32x4 acc3[4][4] = {};
    GEMM2(128 * DD, acc3);
    __syncthreads();
#pragma unroll
    for (int i = 0; i < 4; i++)
#pragma unroll
      for (int q = 0; q < 4; q++) {
        int row = rowb + i * 16 + q;
#pragma unroll
        for (int j = 0; j < 4; j++)
          mem_s[row * 136 + colb + j * 16] = __float2bfloat16(acc3[i][j][q]);
      }
    __syncthreads();
    store_tile(vout);
  }
}

// ================= generic GEMM via gload_lds 2-phase =================
// EPI: 1 bf16 staged | 5 bias+relu->bf16 staged | 6 +x1+b2, LN -> f32 staged
template<int EPI>
__global__ __launch_bounds__(256, 3) void k_gemmG(
    const bf16* __restrict__ A, const bf16* __restrict__ B, void* __restrict__ out,
    const float* __restrict__ bias, const float* __restrict__ aux,
    int M, int K, int lda, int ldc)
{
  __shared__ __align__(16) char smem[36864];
  bf16* const stg = (bf16*)smem;
  float* const red_s = (float*)(smem + 34816);
  float* const red_q = (float*)(smem + 35840);

  const int tid = threadIdx.x, lane = tid & 63, w = tid >> 6;
  const int wm = w >> 1, wn = w & 1;
  const int bm0 = blockIdx.x * BM, bn0 = blockIdx.y * BM;
  const int swzE = ((lane & 3) ^ ((lane >> 3) & 3)) * 8;

  const bf16* pA[2];
  const bf16* pB[2];
#pragma unroll
  for (int r = 0; r < 2; r++) {
    int ra = bm0 + r * 64 + w * 16 + (lane >> 2);
    if (ra > M - 1) ra = M - 1;
    pA[r] = A + (size_t)ra * lda + swzE;
    pB[r] = B + (size_t)(bn0 + r * 64 + w * 16 + (lane >> 2)) * K + swzE;
  }
  auto STAGE = [&](int kb, int buf) {
#pragma unroll
    for (int r = 0; r < 2; r++) {
      gload16(pA[r] + kb * 32, smem + buf * 8192 + r * 4096 + w * 1024);
      gload16(pB[r] + kb * 32, smem + 16384 + buf * 8192 + r * 4096 + w * 1024);
    }
  };

  f32x4 acc[4][4] = {};
  const int KB = K >> 5;
  STAGE(0, 0);
  __syncthreads();
  int buf = 0;
#pragma unroll 1
  for (int kb = 0; kb < KB; kb++) {
    if (kb + 1 < KB) STAGE(kb + 1, buf ^ 1);
    mfma_swz((const bf16*)(smem + buf * 8192), (const bf16*)(smem + 16384 + buf * 8192),
             acc, wm, wn, lane);
    __syncthreads();
    buf ^= 1;
  }

  const int lr = lane & 15, lg = lane >> 4;
  const int colb = wn * 64 + lr;
  const int rowb = wm * 64 + lg * 4;

  if constexpr (EPI == 1 || EPI == 5) {
    if constexpr (EPI == 5) {
#pragma unroll
      for (int j = 0; j < 4; j++) {
        float b = bias[bn0 + colb + j * 16];
#pragma unroll
        for (int i = 0; i < 4; i++)
#pragma unroll
          for (int q = 0; q < 4; q++) acc[i][j][q] = fmaxf(acc[i][j][q] + b, 0.f);
      }
    }
#pragma unroll
    for (int i = 0; i < 4; i++)
#pragma unroll
      for (int q = 0; q < 4; q++) {
        int row = rowb + i * 16 + q;
#pragma unroll
        for (int j = 0; j < 4; j++)
          stg[row * 136 + colb + j * 16] = __float2bfloat16(acc[i][j][q]);
      }
    __syncthreads();
#pragma unroll
    for (int c = 0; c < 8; c++) {
      int off = c * 2048 + tid * 8;
      int row = off >> 7, col = off & 127;
      int r = bm0 + row;
      if (r < M)
        *(uint4*)((bf16*)out + (size_t)r * ldc + bn0 + col) = *(uint4*)&stg[row * 136 + col];
    }
  }

  if constexpr (EPI == 6) {
#pragma unroll
    for (int i = 0; i < 4; i++)
#pragma unroll
      for (int q = 0; q < 4; q++) {
        int r = bm0 + rowb + i * 16 + q;
        if (r < M) {
#pragma unroll
          for (int j = 0; j < 4; j++)
            acc[i][j][q] += bias[colb + j * 16] + aux[(size_t)r * DD + colb + j * 16];
        }
      }
    row_ln_stats(acc, red_s, red_q, wm, wn, lane);
    __syncthreads();
    float* const fstg = (float*)smem;   // [64][132] f32
#pragma unroll
    for (int h = 0; h < 2; h++) {
      if (wm == h) {
#pragma unroll
        for (int i = 0; i < 4; i++)
#pragma unroll
          for (int q = 0; q < 4; q++) {
            int row = rowb + i * 16 + q;
            float Sm = red_s[row] + red_s[128 + row];
            float Qs = red_q[row] + red_q[128 + row];
            float mu = Sm * 0.0078125f;
            float var = Qs * 0.0078125f - mu * mu;
            float inv = 1.0f / sqrtf(var + 1e-5f);
            int rloc = row - h * 64;
#pragma unroll
            for (int j = 0; j < 4; j++)
              fstg[rloc * 132 + colb + j * 16] = (acc[i][j][q] - mu) * inv;
          }
      }
      __syncthreads();
#pragma unroll
      for (int c = 0; c < 8; c++) {
        int boff = c * 4096 + tid * 16;
        int row = boff >> 9, col = (boff & 511) >> 2;
        int r = bm0 + h * 64 + row;
        if (r < M)
          *(float4*)((float*)out + (size_t)r * DD + col) = *(float4*)&fstg[row * 132 + col];
      }
      __syncthreads();
    }
  }
}

// ===== msg GEMM (attn-scaled A, normalization folded) + scatter =====
__global__ __launch_bounds__(256) void k_msg(
    const bf16* __restrict__ Vh, const bf16* __restrict__ Wo,
    float* __restrict__ aggr, const float* __restrict__ evals, const float* __restrict__ nsum,
    const int* __restrict__ e0, const int* __restrict__ e1, const int* __restrict__ e2)
{
  __shared__ __align__(16) bf16 As[128 * 40];
  __shared__ __align__(16) bf16 Bs[128 * 40];
  __shared__ int sdst[128];
  const int tid = threadIdx.x, lane = tid & 63, w = tid >> 6, wm = w >> 1, wn = w & 1;
  const int bm0 = blockIdx.x * BM;
  if (tid < 128) sdst[tid] = edge_dst(bm0 + tid, e0, e1, e2);
  __syncthreads();
  f32x4 acc[4][4] = {};
#pragma unroll 1
  for (int kb = 0; kb < 4; kb++) {
    const int k0 = kb * 32;
    for (int c = tid; c < 512; c += 256) {
      int row = c >> 2, c8 = (c & 3) * 8;
      int e = bm0 + row;
      int h = (k0 + c8) >> 4;
      uint4 v = *(const uint4*)(Vh + (size_t)e * DD + k0 + c8);
      float at = evals[(size_t)e * 8 + h] / (nsum[(size_t)sdst[row] * 8 + h] + 1e-16f);
      union { uint4 u; bf16 hh[8]; } vv; vv.u = v;
#pragma unroll
      for (int t = 0; t < 8; t++)
        vv.hh[t] = __float2bfloat16(at * __bfloat162float(vv.hh[t]));
      *(uint4*)&As[row * 40 + c8] = vv.u;
      *(uint4*)&Bs[row * 40 + c8] = *(const uint4*)(Wo + (size_t)row * DD + k0 + c8);
    }
    __syncthreads();
    mfma_step(As, 40, Bs, 40, acc, wm, wn, lane);
    __syncthreads();
  }
  const int lr = lane & 15, lg = lane >> 4;
  const int colb = wn * 64 + lr;
  const int rowb = wm * 64 + lg * 4;
#pragma unroll
  for (int i = 0; i < 4; i++)
#pragma unroll
    for (int q = 0; q < 4; q++) {
      int dst = sdst[rowb + i * 16 + q];
#pragma unroll
      for (int j = 0; j < 4; j++)
        atomicAdd(aggr + (size_t)dst * DD + colb + j * 16, acc[i][j][q]);
    }
}

// ================= small kernels =================
__device__ __forceinline__ float2 ln_pair(float2 v, float eps) {
  float s = v.x + v.y, sq = v.x * v.x + v.y * v.y;
#pragma unroll
  for (int o = 32; o > 0; o >>= 1) {
    s += __shfl_xor(s, o);
    sq += __shfl_xor(sq, o);
  }
  float mu = s * 0.0078125f;
  float var = sq * 0.0078125f - mu * mu;
  float inv = 1.0f / sqrtf(var + eps);
  return make_float2((v.x - mu) * inv, (v.y - mu) * inv);
}

__global__ void k_init_ea(const float* __restrict__ a2a, const float* __restrict__ l2l,
                          const float* __restrict__ rpe, const float* __restrict__ rpeW,
                          const float* __restrict__ rpeb, bf16* __restrict__ eah) {
  int r = blockIdx.x * 4 + (threadIdx.x >> 6);
  int lane = threadIdx.x & 63;
  int ty = r >> 16, idx = r & 65535;
  int c0 = lane * 2;
  float2 y;
  if (ty < 2) {
    y = *(const float2*)((ty == 0 ? a2a : l2l) + (size_t)idx * DD + c0);
  } else {
    float rp0 = rpe[idx * 5 + 0], rp1 = rpe[idx * 5 + 1], rp2 = rpe[idx * 5 + 2];
    float rp3 = rpe[idx * 5 + 3], rp4 = rpe[idx * 5 + 4];
    float2 v;
    v.x = rpeb[c0]     + rp0 * rpeW[c0 * 5]           + rp1 * rpeW[c0 * 5 + 1]
        + rp2 * rpeW[c0 * 5 + 2]     + rp3 * rpeW[c0 * 5 + 3]     + rp4 * rpeW[c0 * 5 + 4];
    v.y = rpeb[c0 + 1] + rp0 * rpeW[(c0 + 1) * 5]     + rp1 * rpeW[(c0 + 1) * 5 + 1]
        + rp2 * rpeW[(c0 + 1) * 5 + 2] + rp3 * rpeW[(c0 + 1) * 5 + 3] + rp4 * rpeW[(c0 + 1) * 5 + 4];
    y = ln_pair(v, 1e-5f);
    y.x = fmaxf(y.x, 0.f);
    y.y = fmaxf(y.y, 0.f);
  }
  size_t o = (size_t)r * DD + c0;
  eah[o] = __float2bfloat16(y.x);
  eah[o + 1] = __float2bfloat16(y.y);
}

__global__ void k_x1(const float* __restrict__ actors, const float* __restrict__ lanesp,
                     const float* __restrict__ aggr, float* __restrict__ x1,
                     bf16* __restrict__ x1h, int R) {
  int r = blockIdx.x * 4 + (threadIdx.x >> 6);
  if (r >= R) return;
  int lane = threadIdx.x & 63;
  int c0 = lane * 2;
  const float* xp = (r < NACT) ? (actors + (size_t)r * DD) : (lanesp + (size_t)(r - NACT) * DD);
  float2 v = *(const float2*)(xp + c0);
  float2 a = *(const float2*)(aggr + (size_t)r * DD + c0);
  v.x += a.x; v.y += a.y;
  float2 y = ln_pair(v, 1e-5f);
  size_t o = (size_t)r * DD + c0;
  *(float2*)(x1 + o) = y;
  x1h[o] = __float2bfloat16(y.x);
  x1h[o + 1] = __float2bfloat16(y.y);
}

__global__ void k_evals(float* __restrict__ logit, const unsigned* __restrict__ nmax,
                        float* __restrict__ nsum,
                        const int* __restrict__ e0, const int* __restrict__ e1,
                        const int* __restrict__ e2) {
  int gid = blockIdx.x * 256 + threadIdx.x;
  int e = gid >> 3, h = gid & 7;
  int dst = edge_dst(e, e0, e1, e2);
  unsigned u = nmax[(size_t)dst * 8 + h];
  float m = (u & 0x80000000u) ? __uint_as_float(u ^ 0x80000000u) : __uint_as_float(~u);
  float v = expf(logit[gid] - m);
  logit[gid] = v;
  atomicAdd(nsum + (size_t)dst * 8 + h, v);
}

__global__ void k_conv(const float* __restrict__ a, bf16* __restrict__ b, int n) {
  int i = blockIdx.x * 256 + threadIdx.x;
  if (i < n) b[i] = __float2bfloat16(a[i]);
}

__global__ void k_x0h(const float* __restrict__ actors, const float* __restrict__ lanesp,
                      bf16* __restrict__ x0h) {
  int gid = blockIdx.x * 256 + threadIdx.x;
  int n = gid >> 7, c = gid & 127;
  float v = (n < NACT) ? actors[(size_t)n * DD + c] : lanesp[(size_t)(n - NACT) * DD + c];
  x0h[gid] = __float2bfloat16(v);
}

// ================= host =================
extern "C" void kernel_launch(void* const* d_in, const int* in_sizes, int n_in,
                              void* d_out, int out_size, void* d_ws, size_t ws_size,
                              hipStream_t stream) {
  (void)in_sizes; (void)n_in; (void)out_size;
  if (ws_size < (150ull << 20)) return;  // tripwire (ws >= 161MB proven in R2)

  const float* actors = (const float*)d_in[0];
  const float* lanesp = (const float*)d_in[1];
  const float* a2a    = (const float*)d_in[2];
  const float* l2l    = (const float*)d_in[3];
  const float* rpe    = (const float*)d_in[4];
  const float* rpeW   = (const float*)d_in[5];
  const float* rpeb   = (const float*)d_in[6];
  const float* mpW    = (const float*)d_in[7];
  const float* mpb    = (const float*)d_in[8];
  const float* euW    = (const float*)d_in[9];
  const float* eub    = (const float*)d_in[10];
  const float* Wq     = (const float*)d_in[11];
  const float* Wk     = (const float*)d_in[12];
  const float* Wv     = (const float*)d_in[13];
  const float* Wo     = (const float*)d_in[14];
  const float* fW1    = (const float*)d_in[15];
  const float* fb1    = (const float*)d_in[16];
  const float* fW2    = (const float*)d_in[17];
  const float* fb2    = (const float*)d_in[18];
  const int* e0 = (const int*)d_in[27];
  const int* e1 = (const int*)d_in[28];
  const int* e2 = (const int*)d_in[29];

  char* ws = (char*)d_ws;
  bf16* W_MP = (bf16*)ws;            // 147456
  bf16* W_EU = W_MP + 147456;        // 32768
  bf16* W_WQ = W_EU + 32768;         // 16384
  bf16* W_KV = W_WQ + 16384;         // 32768 (K rows 0-127, V rows 128-255)
  bf16* W_WO = W_KV + 32768;         // 16384
  bf16* W_F1 = W_WO + 16384;         // 32768
  bf16* W_F2 = W_F1 + 32768;         // 32768

  bf16*  X0H = (bf16*)(ws + (1ull << 20));    // NN*128 bf16 (later X1H)
  bf16*  QH  = (bf16*)(ws + (12ull << 20));   // NN*128 bf16
  float* POOL = (float*)(ws + (24ull << 20));
  float*    AGGR = POOL;                      // NN*128 f32 (memset AFTER edge pipeline)
  float*    X1   = POOL + 5120000;            // NN*128 f32
  bf16*     PS01 = (bf16*)POOL;               // [NN][512] bf16 = 40.96MB, overlays AGGR+X1
  float*    LOGI = POOL + 10240000;           // EE*8 f32 (raw -> exp)
  unsigned* NMAX = (unsigned*)(POOL + 11812864);  // NN*8
  float*    NSUM = POOL + 12132864;           // NN*8
  bf16* EAH = (bf16*)(ws + (80ull << 20));    // EE*128 bf16
  bf16* VH  = EAH;                            // V aliases EAH (per-row overwrite, safe)
  bf16* PS2 = (bf16*)(ws + (128ull << 20));   // [NN][256] bf16 = 20.5MB
  bf16* X1H = X0H;
  bf16* H1H = EAH;                            // FFN hidden reuses EAH after msg GEMM

  k_conv<<<576, 256, 0, stream>>>(mpW, W_MP, 147456);
  k_conv<<<128, 256, 0, stream>>>(euW, W_EU, 32768);
  k_conv<<<64, 256, 0, stream>>>(Wq + 2 * 16384, W_WQ, 16384);
  k_conv<<<64, 256, 0, stream>>>(Wk + 2 * 16384, W_KV, 16384);
  k_conv<<<64, 256, 0, stream>>>(Wv + 2 * 16384, W_KV + 16384, 16384);
  k_conv<<<64, 256, 0, stream>>>(Wo + 2 * 16384, W_WO, 16384);
  k_conv<<<128, 256, 0, stream>>>(fW1 + 2 * 32768, W_F1, 32768);
  k_conv<<<128, 256, 0, stream>>>(fW2 + 2 * 32768, W_F2, 32768);
  k_x0h<<<20000, 256, 0, stream>>>(actors, lanesp, X0H);
  k_init_ea<<<49152, 256, 0, stream>>>(a2a, l2l, rpe, rpeW, rpeb, EAH);

  // Q = x0 @ Wq^T (bf16), needed by layer-2 logits
  k_gemmG<1><<<313, 256, 0, stream>>>(X0H, W_WQ, QH, nullptr, nullptr, NN, 128, 128, DD);

  // node-level precompute: P_l = x0 @ W_a_l^T, S_l = x0 @ W_b_l^T for l=0,1,2
  k_ps<<<dim3(313, 6), 256, 0, stream>>>(X0H, W_MP, PS01, PS2, NN);

  hipMemsetAsync(NMAX, 0, (size_t)NN * 8 * 4, stream);
  hipMemsetAsync(NSUM, 0, (size_t)NN * 8 * 4, stream);

  // layers 0,1: edge-attr evolution; GEMM1 = ea@W_c + gathered P[dst]+S[src]
  for (int i = 0; i < 2; i++) {
    k_fused<0><<<EE / BM, 256, 0, stream>>>(W_MP + i * 49152, W_EU + i * 16384,
        mpb + i * 128, eub + i * 128, EAH,
        PS01 + i * 256, PS01 + i * 256 + 128, 512,
        nullptr, nullptr, nullptr, nullptr, e0, e1, e2);
  }
  // layer 2: fused cat->mem->{K->logits, V}
  k_fused<1><<<EE / BM, 256, 0, stream>>>(W_MP + 2 * 49152, W_KV,
      mpb + 2 * 128, nullptr, EAH, PS2, PS2 + 128, 256,
      QH, VH, LOGI, NMAX, e0, e1, e2);

  // PS01 now dead -> reclaim region for AGGR/X1
  hipMemsetAsync(AGGR, 0, (size_t)NN * DD * 4, stream);

  k_evals<<<EE * 8 / 256, 256, 0, stream>>>(LOGI, NMAX, NSUM, e0, e1, e2);

  // msg = (attn*V) @ Wo^T, scatter-add into AGGR (attn normalization folded in)
  k_msg<<<EE / BM, 256, 0, stream>>>(VH, W_WO, AGGR, LOGI, NSUM, e0, e1, e2);

  k_x1<<<NN / 4, 256, 0, stream>>>(actors, lanesp, AGGR, X1, X1H, NN);
  k_gemmG<5><<<dim3(313, 2), 256, 0, stream>>>(X1H, W_F1, H1H, fb1 + 2 * 256, nullptr,
                                               NN, 128, 128, 256);
  k_gemmG<6><<<dim3(313, 1), 256, 0, stream>>>(H1H, W_F2, d_out, fb2 + 2 * 128, X1,
                                               NN, 256, 256, DD);
}

// Round 13
// 646.928 us; speedup vs baseline: 1.0001x; 1.0001x over previous
//
#include <hip/hip_runtime.h>
#include <hip/hip_bf16.h>

using bf16 = __hip_bfloat16;
typedef __bf16 bf16x8 __attribute__((ext_vector_type(8)));
typedef float f32x4 __attribute__((ext_vector_type(4)));

constexpr int DD   = 128;
constexpr int NACT = 8000;
constexpr int NN   = 40000;
constexpr int E1   = 65536;
constexpr int EE   = 3 * E1;

#define BM 128

// ---- async global->LDS, 16B per lane; LDS dest = wave-uniform base + lane*16 ----
__device__ __forceinline__ void gload16(const void* g, void* l) {
  __builtin_amdgcn_global_load_lds((const __attribute__((address_space(1))) void*)g,
                                   (__attribute__((address_space(3))) void*)l, 16, 0, 0);
}

__device__ __forceinline__ int edge_dst(int e, const int* e0, const int* e1, const int* e2) {
  int ty = e >> 16, idx = e & 65535;
  const int* ep = (ty == 0) ? e0 : ((ty == 1) ? e1 : e2);
  return ep[E1 + idx];
}
__device__ __forceinline__ int edge_src(int e, const int* e0, const int* e1, const int* e2) {
  int ty = e >> 16, idx = e & 65535;
  const int* ep = (ty == 0) ? e0 : ((ty == 1) ? e1 : e2);
  return ep[idx];
}

// plain pitched LDS mfma step (msg GEMM)
__device__ __forceinline__ void mfma_step(const bf16* A0, int lda, const bf16* B0, int ldb,
                                          f32x4 acc[4][4], int wm, int wn, int lane) {
  const int lr = lane & 15;
  const int lk = (lane >> 4) * 8;
  bf16x8 a[4], b[4];
#pragma unroll
  for (int i = 0; i < 4; i++)
    a[i] = *(const bf16x8*)(A0 + (size_t)(wm * 64 + i * 16 + lr) * lda + lk);
#pragma unroll
  for (int j = 0; j < 4; j++)
    b[j] = *(const bf16x8*)(B0 + (size_t)(wn * 64 + j * 16 + lr) * ldb + lk);
#pragma unroll
  for (int i = 0; i < 4; i++)
#pragma unroll
    for (int j = 0; j < 4; j++)
      acc[i][j] = __builtin_amdgcn_mfma_f32_16x16x32_bf16(a[i], b[j], acc[i][j], 0, 0, 0);
}

// both operands in unpadded [128][32] gload_lds buffers with chunk swizzle
__device__ __forceinline__ void mfma_swz(const bf16* A0, const bf16* B0,
                                         f32x4 acc[4][4], int wm, int wn, int lane) {
  const int lr = lane & 15;
  const int g  = lane >> 4;
  const int sw = (g ^ ((lr >> 1) & 3)) * 8;
  bf16x8 a[4], b[4];
#pragma unroll
  for (int i = 0; i < 4; i++)
    a[i] = *(const bf16x8*)(A0 + (wm * 64 + i * 16 + lr) * 32 + sw);
#pragma unroll
  for (int j = 0; j < 4; j++)
    b[j] = *(const bf16x8*)(B0 + (wn * 64 + j * 16 + lr) * 32 + sw);
#pragma unroll
  for (int i = 0; i < 4; i++)
#pragma unroll
    for (int j = 0; j < 4; j++)
      acc[i][j] = __builtin_amdgcn_mfma_f32_16x16x32_bf16(a[i], b[j], acc[i][j], 0, 0, 0);
}

__device__ __forceinline__ void row_ln_stats(const f32x4 acc[4][4], float* red_s,
                                             float* red_q, int wm, int wn, int lane) {
  const int lr = lane & 15, lg = lane >> 4;
#pragma unroll
  for (int i = 0; i < 4; i++) {
#pragma unroll
    for (int q = 0; q < 4; q++) {
      float s = acc[i][0][q] + acc[i][1][q] + acc[i][2][q] + acc[i][3][q];
      float t = acc[i][0][q] * acc[i][0][q] + acc[i][1][q] * acc[i][1][q]
              + acc[i][2][q] * acc[i][2][q] + acc[i][3][q] * acc[i][3][q];
#pragma unroll
      for (int off = 1; off < 16; off <<= 1) {
        s += __shfl_xor(s, off);
        t += __shfl_xor(t, off);
      }
      if (lr == 0) {
        int row = wm * 64 + i * 16 + lg * 4 + q;
        red_s[wn * 128 + row] = s;
        red_q[wn * 128 + row] = t;
      }
    }
  }
}

// ================= fused edge-layer kernel (gload_lds 2-phase; GEMM2 B direct-to-reg) =====
// LDS: [0,32768) GEMM1 A/B dbuf (4x8KB), aliased by mem_s [0,34816)=[128][136]
//      red [34816,36864) ; idx [36864,37888)  => 37888B -> 4 blocks/CU
template<int LAST>
__global__ __launch_bounds__(256, 4) void k_fused(
    const bf16* __restrict__ Wmp, const bf16* __restrict__ W2,
    const float* __restrict__ mpb, const float* __restrict__ eub,
    bf16* eah, const bf16* __restrict__ x0h,
    const bf16* __restrict__ qh, bf16* vout,
    float* __restrict__ logi, unsigned* __restrict__ nmax,
    const int* __restrict__ e0, const int* __restrict__ e1, const int* __restrict__ e2)
{
  __shared__ __align__(16) char smem[37888];
  bf16* const mem_s = (bf16*)smem;                    // [128][136]
  float* const red_s = (float*)(smem + 34816);
  float* const red_q = (float*)(smem + 35840);
  int* const sdst = (int*)(smem + 36864);
  int* const ssrc = (int*)(smem + 37376);

  const int tid = threadIdx.x;
  const int bm0 = blockIdx.x * BM;
  const int lane = tid & 63, w = tid >> 6, wm = w >> 1, wn = w & 1;
  const int swzE = ((lane & 3) ^ ((lane >> 3) & 3)) * 8;

  if (tid < 128) sdst[tid] = edge_dst(bm0 + tid, e0, e1, e2);
  else           ssrc[tid - 128] = edge_src(bm0 + tid - 128, e0, e1, e2);
  __syncthreads();
  const int mr0 = w * 16 + (lane >> 2), mr1 = 64 + w * 16 + (lane >> 2);
  const int rd0 = sdst[mr0], rd1 = sdst[mr1];
  const int rs0 = ssrc[mr0], rs1 = ssrc[mr1];
  const bf16* pd0 = x0h + (size_t)rd0 * DD + swzE;
  const bf16* pd1 = x0h + (size_t)rd1 * DD + swzE;
  const bf16* ps0 = x0h + (size_t)rs0 * DD + swzE;
  const bf16* ps1 = x0h + (size_t)rs1 * DD + swzE;
  const bf16* pe0 = eah + (size_t)(bm0 + mr0) * DD + swzE;
  const bf16* pe1 = eah + (size_t)(bm0 + mr1) * DD + swzE;
  const bf16* pB0 = Wmp + (size_t)mr0 * 384 + swzE;
  const bf16* pB1 = Wmp + (size_t)mr1 * 384 + swzE;

  auto STAGE1 = [&](int kb, int buf) {
    const bf16 *a0, *a1;
    const int k4 = (kb & 3) * 32;
    if (kb < 4)      { a0 = pd0 + k4; a1 = pd1 + k4; }
    else if (kb < 8) { a0 = ps0 + k4; a1 = ps1 + k4; }
    else             { a0 = pe0 + k4; a1 = pe1 + k4; }
    char* base = smem + buf * 16384;
    gload16(a0, base + w * 1024);
    gload16(a1, base + 4096 + w * 1024);
    gload16(pB0 + kb * 32, base + 8192 + w * 1024);
    gload16(pB1 + kb * 32, base + 12288 + w * 1024);
  };

  // ---- GEMM1: K=384, 2-phase, 1 barrier/step ----
  f32x4 acc[4][4] = {};
  STAGE1(0, 0);
  __syncthreads();
  int buf = 0;
#pragma unroll
  for (int kb = 0; kb < 12; kb++) {
    if (kb < 11) STAGE1(kb + 1, buf ^ 1);
    mfma_swz((const bf16*)(smem + buf * 16384), (const bf16*)(smem + buf * 16384 + 8192),
             acc, wm, wn, lane);
    __syncthreads();
    buf ^= 1;
  }

  const int lr = lane & 15, lg = lane >> 4;
  const int colb = wn * 64 + lr;
  const int rowb = wm * 64 + lg * 4;

  // ---- epilogue 1: bias + LN + relu -> mem_s ----
#pragma unroll
  for (int j = 0; j < 4; j++) {
    float bj = mpb[colb + j * 16];
#pragma unroll
    for (int i = 0; i < 4; i++)
#pragma unroll
      for (int q = 0; q < 4; q++) acc[i][j][q] += bj;
  }
  row_ln_stats(acc, red_s, red_q, wm, wn, lane);
  __syncthreads();
#pragma unroll
  for (int i = 0; i < 4; i++) {
#pragma unroll
    for (int q = 0; q < 4; q++) {
      int row = rowb + i * 16 + q;
      float Sm = red_s[row] + red_s[128 + row];
      float Qs = red_q[row] + red_q[128 + row];
      float mu = Sm * 0.0078125f;
      float var = Qs * 0.0078125f - mu * mu;
      float inv = 1.0f / sqrtf(var + 1e-5f);
#pragma unroll
      for (int j = 0; j < 4; j++)
        mem_s[row * 136 + colb + j * 16] =
            __float2bfloat16(fmaxf((acc[i][j][q] - mu) * inv, 0.f));
    }
  }
  __syncthreads();   // mem_s visible to all waves

  // GEMM2: A = mem_s (LDS), B = W2 rows [vrow, vrow+128) direct-to-reg (L2-hot)
  auto GEMM2 = [&](int vrow, f32x4 a2[4][4]) {
#pragma unroll
    for (int kb = 0; kb < 4; kb++) {
      bf16x8 a[4], b[4];
#pragma unroll
      for (int j = 0; j < 4; j++)
        b[j] = *(const bf16x8*)(W2 + (size_t)(vrow + wn * 64 + j * 16 + lr) * DD
                                + kb * 32 + lg * 8);
#pragma unroll
      for (int i = 0; i < 4; i++)
        a[i] = *(const bf16x8*)(mem_s + (size_t)(wm * 64 + i * 16 + lr) * 136
                                + kb * 32 + lg * 8);
#pragma unroll
      for (int i = 0; i < 4; i++)
#pragma unroll
        for (int j = 0; j < 4; j++)
          a2[i][j] = __builtin_amdgcn_mfma_f32_16x16x32_bf16(a[i], b[j], a2[i][j], 0, 0, 0);
    }
  };
  auto store_tile = [&](bf16* dst) {
#pragma unroll
    for (int c = 0; c < 8; c++) {
      int off = c * 2048 + tid * 8;
      int row = off >> 7, col = off & 127;
      *(uint4*)(dst + (size_t)bm0 * DD + off) = *(uint4*)&mem_s[row * 136 + col];
    }
  };

  if constexpr (LAST == 0) {
    f32x4 acc2[4][4] = {};
    GEMM2(0, acc2);
    // delta = relu(LN(acc2+eub)); ea = LN(ea + delta)
#pragma unroll
    for (int j = 0; j < 4; j++) {
      float bj = eub[colb + j * 16];
#pragma unroll
      for (int i = 0; i < 4; i++)
#pragma unroll
        for (int q = 0; q < 4; q++) acc2[i][j][q] += bj;
    }
    __syncthreads();
    row_ln_stats(acc2, red_s, red_q, wm, wn, lane);
    __syncthreads();
#pragma unroll
    for (int i = 0; i < 4; i++) {
#pragma unroll
      for (int q = 0; q < 4; q++) {
        int row = rowb + i * 16 + q;
        float Sm = red_s[row] + red_s[128 + row];
        float Qs = red_q[row] + red_q[128 + row];
        float mu = Sm * 0.0078125f;
        float var = Qs * 0.0078125f - mu * mu;
        float inv = 1.0f / sqrtf(var + 1e-5f);
        int r = bm0 + row;
#pragma unroll
        for (int j = 0; j < 4; j++) {
          float d = fmaxf((acc2[i][j][q] - mu) * inv, 0.f);
          float eo = __bfloat162float(eah[(size_t)r * DD + colb + j * 16]);
          acc2[i][j][q] = eo + d;
        }
      }
    }
    __syncthreads();
    row_ln_stats(acc2, red_s, red_q, wm, wn, lane);
    __syncthreads();
#pragma unroll
    for (int i = 0; i < 4; i++) {
#pragma unroll
      for (int q = 0; q < 4; q++) {
        int row = rowb + i * 16 + q;
        float Sm = red_s[row] + red_s[128 + row];
        float Qs = red_q[row] + red_q[128 + row];
        float mu = Sm * 0.0078125f;
        float var = Qs * 0.0078125f - mu * mu;
        float inv = 1.0f / sqrtf(var + 1e-5f);
#pragma unroll
        for (int j = 0; j < 4; j++)
          mem_s[row * 136 + colb + j * 16] =
              __float2bfloat16((acc2[i][j][q] - mu) * inv);
      }
    }
    __syncthreads();
    store_tile(eah);
  } else {
    // ---- K = mem @ W_K^T ; logits in-register ----
    f32x4 acc2[4][4] = {};
    GEMM2(0, acc2);
#pragma unroll
    for (int i = 0; i < 4; i++) {
#pragma unroll
      for (int q = 0; q < 4; q++) {
        int row = rowb + i * 16 + q;
        int dst = sdst[row];
#pragma unroll
        for (int j = 0; j < 4; j++) {
          int h = wn * 4 + j;
          float qv = __bfloat162float(qh[(size_t)dst * DD + h * 16 + lr]);
          float p = acc2[i][j][q] * qv;
#pragma unroll
          for (int off = 1; off < 16; off <<= 1) p += __shfl_xor(p, off);
          if (lr == 0) {
            p *= 0.25f;
            int e = bm0 + row;
            logi[(size_t)e * 8 + h] = p;
            unsigned u = __float_as_uint(p);
            u = (u & 0x80000000u) ? ~u : (u | 0x80000000u);
            atomicMax(nmax + (size_t)dst * 8 + h, u);
          }
        }
      }
    }
    // ---- V = mem @ W_V^T ----
    f32x4 acc3[4][4] = {};
    GEMM2(128, acc3);
    __syncthreads();
#pragma unroll
    for (int i = 0; i < 4; i++)
#pragma unroll
      for (int q = 0; q < 4; q++) {
        int row = rowb + i * 16 + q;
#pragma unroll
        for (int j = 0; j < 4; j++)
          mem_s[row * 136 + colb + j * 16] = __float2bfloat16(acc3[i][j][q]);
      }
    __syncthreads();
    store_tile(vout);
  }
}

// ================= generic GEMM via gload_lds 2-phase =================
// EPI: 1 bf16 staged | 5 bias+relu->bf16 staged | 6 +x1+b2, LN -> f32 staged
template<int EPI>
__global__ __launch_bounds__(256, 4) void k_gemmG(
    const bf16* __restrict__ A, const bf16* __restrict__ B, void* __restrict__ out,
    const float* __restrict__ bias, const float* __restrict__ aux,
    int M, int K, int lda, int ldc)
{
  __shared__ __align__(16) char smem[36864];
  bf16* const stg = (bf16*)smem;                 // [128][136] (aliases stage bufs)
  float* const red_s = (float*)(smem + 34816);
  float* const red_q = (float*)(smem + 35840);

  const int tid = threadIdx.x, lane = tid & 63, w = tid >> 6;
  const int wm = w >> 1, wn = w & 1;
  const int bm0 = blockIdx.x * BM, bn0 = blockIdx.y * BM;
  const int swzE = ((lane & 3) ^ ((lane >> 3) & 3)) * 8;

  const bf16* pA[2];
  const bf16* pB[2];
#pragma unroll
  for (int r = 0; r < 2; r++) {
    int ra = bm0 + r * 64 + w * 16 + (lane >> 2);
    if (ra > M - 1) ra = M - 1;
    pA[r] = A + (size_t)ra * lda + swzE;
    pB[r] = B + (size_t)(bn0 + r * 64 + w * 16 + (lane >> 2)) * K + swzE;
  }
  auto STAGE = [&](int kb, int buf) {
#pragma unroll
    for (int r = 0; r < 2; r++) {
      gload16(pA[r] + kb * 32, smem + buf * 8192 + r * 4096 + w * 1024);
      gload16(pB[r] + kb * 32, smem + 16384 + buf * 8192 + r * 4096 + w * 1024);
    }
  };

  f32x4 acc[4][4] = {};
  const int KB = K >> 5;
  STAGE(0, 0);
  __syncthreads();
  int buf = 0;
#pragma unroll 1
  for (int kb = 0; kb < KB; kb++) {
    if (kb + 1 < KB) STAGE(kb + 1, buf ^ 1);
    mfma_swz((const bf16*)(smem + buf * 8192), (const bf16*)(smem + 16384 + buf * 8192),
             acc, wm, wn, lane);
    __syncthreads();
    buf ^= 1;
  }

  const int lr = lane & 15, lg = lane >> 4;
  const int colb = wn * 64 + lr;
  const int rowb = wm * 64 + lg * 4;

  if constexpr (EPI == 1 || EPI == 5) {
    if constexpr (EPI == 5) {
#pragma unroll
      for (int j = 0; j < 4; j++) {
        float b = bias[bn0 + colb + j * 16];
#pragma unroll
        for (int i = 0; i < 4; i++)
#pragma unroll
          for (int q = 0; q < 4; q++) acc[i][j][q] = fmaxf(acc[i][j][q] + b, 0.f);
      }
    }
#pragma unroll
    for (int i = 0; i < 4; i++)
#pragma unroll
      for (int q = 0; q < 4; q++) {
        int row = rowb + i * 16 + q;
#pragma unroll
        for (int j = 0; j < 4; j++)
          stg[row * 136 + colb + j * 16] = __float2bfloat16(acc[i][j][q]);
      }
    __syncthreads();
#pragma unroll
    for (int c = 0; c < 8; c++) {
      int off = c * 2048 + tid * 8;
      int row = off >> 7, col = off & 127;
      int r = bm0 + row;
      if (r < M)
        *(uint4*)((bf16*)out + (size_t)r * ldc + bn0 + col) = *(uint4*)&stg[row * 136 + col];
    }
  }

  if constexpr (EPI == 6) {
#pragma unroll
    for (int i = 0; i < 4; i++)
#pragma unroll
      for (int q = 0; q < 4; q++) {
        int r = bm0 + rowb + i * 16 + q;
        if (r < M) {
#pragma unroll
          for (int j = 0; j < 4; j++)
            acc[i][j][q] += bias[colb + j * 16] + aux[(size_t)r * DD + colb + j * 16];
        }
      }
    row_ln_stats(acc, red_s, red_q, wm, wn, lane);
    __syncthreads();
    float* const fstg = (float*)smem;   // [64][132] f32
#pragma unroll
    for (int h = 0; h < 2; h++) {
      if (wm == h) {
#pragma unroll
        for (int i = 0; i < 4; i++)
#pragma unroll
          for (int q = 0; q < 4; q++) {
            int row = rowb + i * 16 + q;
            float Sm = red_s[row] + red_s[128 + row];
            float Qs = red_q[row] + red_q[128 + row];
            float mu = Sm * 0.0078125f;
            float var = Qs * 0.0078125f - mu * mu;
            float inv = 1.0f / sqrtf(var + 1e-5f);
            int rloc = row - h * 64;
#pragma unroll
            for (int j = 0; j < 4; j++)
              fstg[rloc * 132 + colb + j * 16] = (acc[i][j][q] - mu) * inv;
          }
      }
      __syncthreads();
#pragma unroll
      for (int c = 0; c < 8; c++) {
        int boff = c * 4096 + tid * 16;
        int row = boff >> 9, col = (boff & 511) >> 2;
        int r = bm0 + h * 64 + row;
        if (r < M)
          *(float4*)((float*)out + (size_t)r * DD + col) = *(float4*)&fstg[row * 132 + col];
      }
      __syncthreads();
    }
  }
}

// ===== msg GEMM (attn-scaled A, reg-staged; evals/nsum normalization folded) + scatter =====
__global__ __launch_bounds__(256) void k_msg(
    const bf16* __restrict__ Vh, const bf16* __restrict__ Wo,
    float* __restrict__ aggr, const float* __restrict__ evals, const float* __restrict__ nsum,
    const int* __restrict__ e0, const int* __restrict__ e1, const int* __restrict__ e2)
{
  __shared__ __align__(16) bf16 As[128 * 40];
  __shared__ __align__(16) bf16 Bs[128 * 40];
  __shared__ int sdst[128];
  const int tid = threadIdx.x, lane = tid & 63, w = tid >> 6, wm = w >> 1, wn = w & 1;
  const int bm0 = blockIdx.x * BM;
  if (tid < 128) sdst[tid] = edge_dst(bm0 + tid, e0, e1, e2);
  __syncthreads();
  f32x4 acc[4][4] = {};
#pragma unroll 1
  for (int kb = 0; kb < 4; kb++) {
    const int k0 = kb * 32;
    for (int c = tid; c < 512; c += 256) {
      int row = c >> 2, c8 = (c & 3) * 8;
      int e = bm0 + row;
      int h = (k0 + c8) >> 4;
      uint4 v = *(const uint4*)(Vh + (size_t)e * DD + k0 + c8);
      float at = evals[(size_t)e * 8 + h] / (nsum[(size_t)sdst[row] * 8 + h] + 1e-16f);
      union { uint4 u; bf16 hh[8]; } vv; vv.u = v;
#pragma unroll
      for (int t = 0; t < 8; t++)
        vv.hh[t] = __float2bfloat16(at * __bfloat162float(vv.hh[t]));
      *(uint4*)&As[row * 40 + c8] = vv.u;
      *(uint4*)&Bs[row * 40 + c8] = *(const uint4*)(Wo + (size_t)row * DD + k0 + c8);
    }
    __syncthreads();
    mfma_step(As, 40, Bs, 40, acc, wm, wn, lane);
    __syncthreads();
  }
  const int lr = lane & 15, lg = lane >> 4;
  const int colb = wn * 64 + lr;
  const int rowb = wm * 64 + lg * 4;
#pragma unroll
  for (int i = 0; i < 4; i++)
#pragma unroll
    for (int q = 0; q < 4; q++) {
      int dst = sdst[rowb + i * 16 + q];
#pragma unroll
      for (int j = 0; j < 4; j++)
        atomicAdd(aggr + (size_t)dst * DD + colb + j * 16, acc[i][j][q]);
    }
}

// ================= small kernels =================
__device__ __forceinline__ float2 ln_pair(float2 v, float eps) {
  float s = v.x + v.y, sq = v.x * v.x + v.y * v.y;
#pragma unroll
  for (int o = 32; o > 0; o >>= 1) {
    s += __shfl_xor(s, o);
    sq += __shfl_xor(sq, o);
  }
  float mu = s * 0.0078125f;
  float var = sq * 0.0078125f - mu * mu;
  float inv = 1.0f / sqrtf(var + eps);
  return make_float2((v.x - mu) * inv, (v.y - mu) * inv);
}

__global__ void k_init_ea(const float* __restrict__ a2a, const float* __restrict__ l2l,
                          const float* __restrict__ rpe, const float* __restrict__ rpeW,
                          const float* __restrict__ rpeb, bf16* __restrict__ eah) {
  int r = blockIdx.x * 4 + (threadIdx.x >> 6);
  int lane = threadIdx.x & 63;
  int ty = r >> 16, idx = r & 65535;
  int c0 = lane * 2;
  float2 y;
  if (ty < 2) {
    y = *(const float2*)((ty == 0 ? a2a : l2l) + (size_t)idx * DD + c0);
  } else {
    float rp0 = rpe[idx * 5 + 0], rp1 = rpe[idx * 5 + 1], rp2 = rpe[idx * 5 + 2];
    float rp3 = rpe[idx * 5 + 3], rp4 = rpe[idx * 5 + 4];
    float2 v;
    v.x = rpeb[c0]     + rp0 * rpeW[c0 * 5]           + rp1 * rpeW[c0 * 5 + 1]
        + rp2 * rpeW[c0 * 5 + 2]     + rp3 * rpeW[c0 * 5 + 3]     + rp4 * rpeW[c0 * 5 + 4];
    v.y = rpeb[c0 + 1] + rp0 * rpeW[(c0 + 1) * 5]     + rp1 * rpeW[(c0 + 1) * 5 + 1]
        + rp2 * rpeW[(c0 + 1) * 5 + 2] + rp3 * rpeW[(c0 + 1) * 5 + 3] + rp4 * rpeW[(c0 + 1) * 5 + 4];
    y = ln_pair(v, 1e-5f);
    y.x = fmaxf(y.x, 0.f);
    y.y = fmaxf(y.y, 0.f);
  }
  size_t o = (size_t)r * DD + c0;
  eah[o] = __float2bfloat16(y.x);
  eah[o + 1] = __float2bfloat16(y.y);
}

__global__ void k_x1(const float* __restrict__ actors, const float* __restrict__ lanesp,
                     const float* __restrict__ aggr, float* __restrict__ x1,
                     bf16* __restrict__ x1h, int R) {
  int r = blockIdx.x * 4 + (threadIdx.x >> 6);
  if (r >= R) return;
  int lane = threadIdx.x & 63;
  int c0 = lane * 2;
  const float* xp = (r < NACT) ? (actors + (size_t)r * DD) : (lanesp + (size_t)(r - NACT) * DD);
  float2 v = *(const float2*)(xp + c0);
  float2 a = *(const float2*)(aggr + (size_t)r * DD + c0);
  v.x += a.x; v.y += a.y;
  float2 y = ln_pair(v, 1e-5f);
  size_t o = (size_t)r * DD + c0;
  *(float2*)(x1 + o) = y;
  x1h[o] = __float2bfloat16(y.x);
  x1h[o + 1] = __float2bfloat16(y.y);
}

__global__ void k_evals(float* __restrict__ logit, const unsigned* __restrict__ nmax,
                        float* __restrict__ nsum,
                        const int* __restrict__ e0, const int* __restrict__ e1,
                        const int* __restrict__ e2) {
  int gid = blockIdx.x * 256 + threadIdx.x;
  int e = gid >> 3, h = gid & 7;
  int dst = edge_dst(e, e0, e1, e2);
  unsigned u = nmax[(size_t)dst * 8 + h];
  float m = (u & 0x80000000u) ? __uint_as_float(u ^ 0x80000000u) : __uint_as_float(~u);
  float v = expf(logit[gid] - m);
  logit[gid] = v;
  atomicAdd(nsum + (size_t)dst * 8 + h, v);
}

__global__ void k_conv(const float* __restrict__ a, bf16* __restrict__ b, int n) {
  int i = blockIdx.x * 256 + threadIdx.x;
  if (i < n) b[i] = __float2bfloat16(a[i]);
}

__global__ void k_x0h(const float* __restrict__ actors, const float* __restrict__ lanesp,
                      bf16* __restrict__ x0h) {
  int gid = blockIdx.x * 256 + threadIdx.x;
  int n = gid >> 7, c = gid & 127;
  float v = (n < NACT) ? actors[(size_t)n * DD + c] : lanesp[(size_t)(n - NACT) * DD + c];
  x0h[gid] = __float2bfloat16(v);
}

// ================= host =================
extern "C" void kernel_launch(void* const* d_in, const int* in_sizes, int n_in,
                              void* d_out, int out_size, void* d_ws, size_t ws_size,
                              hipStream_t stream) {
  (void)in_sizes; (void)n_in; (void)out_size;
  if (ws_size < (128ull << 20)) return;  // tripwire

  const float* actors = (const float*)d_in[0];
  const float* lanesp = (const float*)d_in[1];
  const float* a2a    = (const float*)d_in[2];
  const float* l2l    = (const float*)d_in[3];
  const float* rpe    = (const float*)d_in[4];
  const float* rpeW   = (const float*)d_in[5];
  const float* rpeb   = (const float*)d_in[6];
  const float* mpW    = (const float*)d_in[7];
  const float* mpb    = (const float*)d_in[8];
  const float* euW    = (const float*)d_in[9];
  const float* eub    = (const float*)d_in[10];
  const float* Wq     = (const float*)d_in[11];
  const float* Wk     = (const float*)d_in[12];
  const float* Wv     = (const float*)d_in[13];
  const float* Wo     = (const float*)d_in[14];
  const float* fW1    = (const float*)d_in[15];
  const float* fb1    = (const float*)d_in[16];
  const float* fW2    = (const float*)d_in[17];
  const float* fb2    = (const float*)d_in[18];
  const int* e0 = (const int*)d_in[27];
  const int* e1 = (const int*)d_in[28];
  const int* e2 = (const int*)d_in[29];

  char* ws = (char*)d_ws;
  bf16* W_MP = (bf16*)ws;            // 147456
  bf16* W_EU = W_MP + 147456;        // 32768
  bf16* W_WQ = W_EU + 32768;         // 16384
  bf16* W_KV = W_WQ + 16384;         // 32768 (K rows 0-127, V rows 128-255)
  bf16* W_WO = W_KV + 32768;         // 16384
  bf16* W_F1 = W_WO + 16384;         // 32768
  bf16* W_F2 = W_F1 + 32768;         // 32768

  bf16*  X0H = (bf16*)(ws + (1ull << 20));    // NN*128 bf16 (later X1H)
  bf16*  QH  = (bf16*)(ws + (12ull << 20));   // NN*128 bf16
  float* POOL = (float*)(ws + (24ull << 20));
  float*    AGGR = POOL;                      // NN*128 f32
  float*    X1   = POOL + 5120000;            // NN*128 f32
  float*    LOGI = POOL + 10240000;           // EE*8 f32 (raw -> exp)
  unsigned* NMAX = (unsigned*)(POOL + 11812864);  // NN*8
  float*    NSUM = POOL + 12132864;           // NN*8
  bf16* EAH = (bf16*)(ws + (80ull << 20));    // EE*128 bf16
  bf16* VH  = EAH;                            // V aliases EAH (per-row overwrite, safe)
  bf16* X1H = X0H;
  bf16* H1H = EAH;                            // FFN hidden reuses EAH after msg GEMM

  k_conv<<<576, 256, 0, stream>>>(mpW, W_MP, 147456);
  k_conv<<<128, 256, 0, stream>>>(euW, W_EU, 32768);
  k_conv<<<64, 256, 0, stream>>>(Wq + 2 * 16384, W_WQ, 16384);
  k_conv<<<64, 256, 0, stream>>>(Wk + 2 * 16384, W_KV, 16384);
  k_conv<<<64, 256, 0, stream>>>(Wv + 2 * 16384, W_KV + 16384, 16384);
  k_conv<<<64, 256, 0, stream>>>(Wo + 2 * 16384, W_WO, 16384);
  k_conv<<<128, 256, 0, stream>>>(fW1 + 2 * 32768, W_F1, 32768);
  k_conv<<<128, 256, 0, stream>>>(fW2 + 2 * 32768, W_F2, 32768);
  k_x0h<<<20000, 256, 0, stream>>>(actors, lanesp, X0H);
  k_init_ea<<<49152, 256, 0, stream>>>(a2a, l2l, rpe, rpeW, rpeb, EAH);

  // Q = x0 @ Wq^T (bf16), needed by layer-2 logits
  k_gemmG<1><<<313, 256, 0, stream>>>(X0H, W_WQ, QH, nullptr, nullptr, NN, 128, 128, DD);

  hipMemsetAsync(AGGR, 0, (size_t)NN * DD * 4, stream);
  hipMemsetAsync(NMAX, 0, (size_t)NN * 8 * 4, stream);
  hipMemsetAsync(NSUM, 0, (size_t)NN * 8 * 4, stream);

  // layers 0,1: fused edge-attr evolution (node state resets to token0 via DDC)
  for (int i = 0; i < 2; i++) {
    k_fused<0><<<EE / BM, 256, 0, stream>>>(W_MP + i * 49152, W_EU + i * 16384,
        mpb + i * 128, eub + i * 128, EAH, X0H, nullptr, nullptr,
        nullptr, nullptr, e0, e1, e2);
  }
  // layer 2: fused cat->mem->{K->logits, V}
  k_fused<1><<<EE / BM, 256, 0, stream>>>(W_MP + 2 * 49152, W_KV,
      mpb + 2 * 128, nullptr, EAH, X0H, QH, VH, LOGI, NMAX, e0, e1, e2);

  k_evals<<<EE * 8 / 256, 256, 0, stream>>>(LOGI, NMAX, NSUM, e0, e1, e2);

  // msg = (attn*V) @ Wo^T, scatter-add into AGGR (attn normalization folded in)
  k_msg<<<EE / BM, 256, 0, stream>>>(VH, W_WO, AGGR, LOGI, NSUM, e0, e1, e2);

  k_x1<<<NN / 4, 256, 0, stream>>>(actors, lanesp, AGGR, X1, X1H, NN);
  k_gemmG<5><<<dim3(313, 2), 256, 0, stream>>>(X1H, W_F1, H1H, fb1 + 2 * 256, nullptr,
                                               NN, 128, 128, 256);
  k_gemmG<6><<<dim3(313, 1), 256, 0, stream>>>(H1H, W_F2, d_out, fb2 + 2 * 128, X1,
                                               NN, 256, 256, DD);
}

// Round 14
// 527.014 us; speedup vs baseline: 1.2276x; 1.2275x over previous
//
#include <hip/hip_runtime.h>
#include <hip/hip_bf16.h>

using bf16 = __hip_bfloat16;
typedef __bf16 bf16x8 __attribute__((ext_vector_type(8)));
typedef float f32x4 __attribute__((ext_vector_type(4)));

constexpr int DD   = 128;
constexpr int NACT = 8000;
constexpr int NN   = 40000;
constexpr int E1   = 65536;
constexpr int EE   = 3 * E1;

#define BM 128

// ---- async global->LDS, 16B per lane; LDS dest = wave-uniform base + lane*16 ----
__device__ __forceinline__ void gload16(const void* g, void* l) {
  __builtin_amdgcn_global_load_lds((const __attribute__((address_space(1))) void*)g,
                                   (__attribute__((address_space(3))) void*)l, 16, 0, 0);
}

__device__ __forceinline__ int edge_dst(int e, const int* e0, const int* e1, const int* e2) {
  int ty = e >> 16, idx = e & 65535;
  const int* ep = (ty == 0) ? e0 : ((ty == 1) ? e1 : e2);
  return ep[E1 + idx];
}
__device__ __forceinline__ int edge_src(int e, const int* e0, const int* e1, const int* e2) {
  int ty = e >> 16, idx = e & 65535;
  const int* ep = (ty == 0) ? e0 : ((ty == 1) ? e1 : e2);
  return ep[idx];
}

// plain pitched LDS mfma step (msg GEMM)
__device__ __forceinline__ void mfma_step(const bf16* A0, int lda, const bf16* B0, int ldb,
                                          f32x4 acc[4][4], int wm, int wn, int lane) {
  const int lr = lane & 15;
  const int lk = (lane >> 4) * 8;
  bf16x8 a[4], b[4];
#pragma unroll
  for (int i = 0; i < 4; i++)
    a[i] = *(const bf16x8*)(A0 + (size_t)(wm * 64 + i * 16 + lr) * lda + lk);
#pragma unroll
  for (int j = 0; j < 4; j++)
    b[j] = *(const bf16x8*)(B0 + (size_t)(wn * 64 + j * 16 + lr) * ldb + lk);
#pragma unroll
  for (int i = 0; i < 4; i++)
#pragma unroll
    for (int j = 0; j < 4; j++)
      acc[i][j] = __builtin_amdgcn_mfma_f32_16x16x32_bf16(a[i], b[j], acc[i][j], 0, 0, 0);
}

// both operands in unpadded [128][32] gload_lds buffers with chunk swizzle
__device__ __forceinline__ void mfma_swz(const bf16* A0, const bf16* B0,
                                         f32x4 acc[4][4], int wm, int wn, int lane) {
  const int lr = lane & 15;
  const int g  = lane >> 4;
  const int sw = (g ^ ((lr >> 1) & 3)) * 8;
  bf16x8 a[4], b[4];
#pragma unroll
  for (int i = 0; i < 4; i++)
    a[i] = *(const bf16x8*)(A0 + (wm * 64 + i * 16 + lr) * 32 + sw);
#pragma unroll
  for (int j = 0; j < 4; j++)
    b[j] = *(const bf16x8*)(B0 + (wn * 64 + j * 16 + lr) * 32 + sw);
#pragma unroll
  for (int i = 0; i < 4; i++)
#pragma unroll
    for (int j = 0; j < 4; j++)
      acc[i][j] = __builtin_amdgcn_mfma_f32_16x16x32_bf16(a[i], b[j], acc[i][j], 0, 0, 0);
}

// A from pitched mem_s, B from swizzled gload buffer
__device__ __forceinline__ void mfma_mixed(const bf16* Am, int lda, const bf16* B0,
                                           f32x4 acc[4][4], int wm, int wn, int lane) {
  const int lr = lane & 15;
  const int g  = lane >> 4;
  const int sw = (g ^ ((lr >> 1) & 3)) * 8;
  bf16x8 a[4], b[4];
#pragma unroll
  for (int i = 0; i < 4; i++)
    a[i] = *(const bf16x8*)(Am + (size_t)(wm * 64 + i * 16 + lr) * lda + g * 8);
#pragma unroll
  for (int j = 0; j < 4; j++)
    b[j] = *(const bf16x8*)(B0 + (wn * 64 + j * 16 + lr) * 32 + sw);
#pragma unroll
  for (int i = 0; i < 4; i++)
#pragma unroll
    for (int j = 0; j < 4; j++)
      acc[i][j] = __builtin_amdgcn_mfma_f32_16x16x32_bf16(a[i], b[j], acc[i][j], 0, 0, 0);
}

__device__ __forceinline__ void row_ln_stats(const f32x4 acc[4][4], float* red_s,
                                             float* red_q, int wm, int wn, int lane) {
  const int lr = lane & 15, lg = lane >> 4;
#pragma unroll
  for (int i = 0; i < 4; i++) {
#pragma unroll
    for (int q = 0; q < 4; q++) {
      float s = acc[i][0][q] + acc[i][1][q] + acc[i][2][q] + acc[i][3][q];
      float t = acc[i][0][q] * acc[i][0][q] + acc[i][1][q] * acc[i][1][q]
              + acc[i][2][q] * acc[i][2][q] + acc[i][3][q] * acc[i][3][q];
#pragma unroll
      for (int off = 1; off < 16; off <<= 1) {
        s += __shfl_xor(s, off);
        t += __shfl_xor(t, off);
      }
      if (lr == 0) {
        int row = wm * 64 + i * 16 + lg * 4 + q;
        red_s[wn * 128 + row] = s;
        red_q[wn * 128 + row] = t;
      }
    }
  }
}

// ================= fused edge-layer kernel (gload_lds 2-phase, R5-proven) =================
// LDS: [0,32768) GEMM1 A/B dbuf (4x8KB), aliased by mem_s [0,34816)=[128][136]
//      [34816,43008) Bs2 [128][32] ; [43008,45056) red ; [45056,46080) idx
template<int LAST>
__global__ __launch_bounds__(256, 3) void k_fused(
    const bf16* __restrict__ Wmp, const bf16* __restrict__ W2,
    const float* __restrict__ mpb, const float* __restrict__ eub,
    bf16* eah, const bf16* __restrict__ x0h,
    const bf16* __restrict__ qh, bf16* vout,
    float* __restrict__ logi, unsigned* __restrict__ nmax,
    const int* __restrict__ e0, const int* __restrict__ e1, const int* __restrict__ e2)
{
  __shared__ __align__(16) char smem[46080];
  bf16* const mem_s = (bf16*)smem;                    // [128][136]
  bf16* const Bs2   = (bf16*)(smem + 34816);          // [128][32]
  float* const red_s = (float*)(smem + 43008);
  float* const red_q = (float*)(smem + 44032);
  int* const sdst = (int*)(smem + 45056);
  int* const ssrc = (int*)(smem + 45568);

  const int tid = threadIdx.x;
  const int bm0 = blockIdx.x * BM;
  const int lane = tid & 63, w = tid >> 6, wm = w >> 1, wn = w & 1;
  const int swzE = ((lane & 3) ^ ((lane >> 3) & 3)) * 8;

  if (tid < 128) sdst[tid] = edge_dst(bm0 + tid, e0, e1, e2);
  else           ssrc[tid - 128] = edge_src(bm0 + tid - 128, e0, e1, e2);
  __syncthreads();
  const int mr0 = w * 16 + (lane >> 2), mr1 = 64 + w * 16 + (lane >> 2);
  const int rd0 = sdst[mr0], rd1 = sdst[mr1];
  const int rs0 = ssrc[mr0], rs1 = ssrc[mr1];
  const bf16* pd0 = x0h + (size_t)rd0 * DD + swzE;
  const bf16* pd1 = x0h + (size_t)rd1 * DD + swzE;
  const bf16* ps0 = x0h + (size_t)rs0 * DD + swzE;
  const bf16* ps1 = x0h + (size_t)rs1 * DD + swzE;
  const bf16* pe0 = eah + (size_t)(bm0 + mr0) * DD + swzE;
  const bf16* pe1 = eah + (size_t)(bm0 + mr1) * DD + swzE;
  const bf16* pB0 = Wmp + (size_t)mr0 * 384 + swzE;
  const bf16* pB1 = Wmp + (size_t)mr1 * 384 + swzE;
  const bf16* pW20 = W2 + (size_t)mr0 * DD + swzE;
  const bf16* pW21 = W2 + (size_t)mr1 * DD + swzE;

  auto STAGE1 = [&](int kb, int buf) {
    const bf16 *a0, *a1;
    const int k4 = (kb & 3) * 32;
    if (kb < 4)      { a0 = pd0 + k4; a1 = pd1 + k4; }
    else if (kb < 8) { a0 = ps0 + k4; a1 = ps1 + k4; }
    else             { a0 = pe0 + k4; a1 = pe1 + k4; }
    char* base = smem + buf * 16384;
    gload16(a0, base + w * 1024);
    gload16(a1, base + 4096 + w * 1024);
    gload16(pB0 + kb * 32, base + 8192 + w * 1024);
    gload16(pB1 + kb * 32, base + 12288 + w * 1024);
  };

  // ---- GEMM1: K=384, 2-phase, 1 barrier/step ----
  f32x4 acc[4][4] = {};
  STAGE1(0, 0);
  __syncthreads();
  int buf = 0;
#pragma unroll
  for (int kb = 0; kb < 12; kb++) {
    if (kb < 11) STAGE1(kb + 1, buf ^ 1);
    mfma_swz((const bf16*)(smem + buf * 16384), (const bf16*)(smem + buf * 16384 + 8192),
             acc, wm, wn, lane);
    __syncthreads();
    buf ^= 1;
  }

  const int lr = lane & 15, lg = lane >> 4;
  const int colb = wn * 64 + lr;
  const int rowb = wm * 64 + lg * 4;

  // ---- epilogue 1: bias + LN + relu -> mem_s ----
#pragma unroll
  for (int j = 0; j < 4; j++) {
    float bj = mpb[colb + j * 16];
#pragma unroll
    for (int i = 0; i < 4; i++)
#pragma unroll
      for (int q = 0; q < 4; q++) acc[i][j][q] += bj;
  }
  row_ln_stats(acc, red_s, red_q, wm, wn, lane);
  __syncthreads();
#pragma unroll
  for (int i = 0; i < 4; i++) {
#pragma unroll
    for (int q = 0; q < 4; q++) {
      int row = rowb + i * 16 + q;
      float Sm = red_s[row] + red_s[128 + row];
      float Qs = red_q[row] + red_q[128 + row];
      float mu = Sm * 0.0078125f;
      float var = Qs * 0.0078125f - mu * mu;
      float inv = 1.0f / sqrtf(var + 1e-5f);
#pragma unroll
      for (int j = 0; j < 4; j++)
        mem_s[row * 136 + colb + j * 16] =
            __float2bfloat16(fmaxf((acc[i][j][q] - mu) * inv, 0.f));
    }
  }
  // (visibility of mem_s: first barrier inside GEMM2 loop)

  auto GEMM2 = [&](int voff, f32x4 a2[4][4]) {
#pragma unroll 1
    for (int kb = 0; kb < 4; kb++) {
      __syncthreads();
      gload16(pW20 + voff + kb * 32, smem + 34816 + w * 1024);
      gload16(pW21 + voff + kb * 32, smem + 34816 + 4096 + w * 1024);
      __syncthreads();
      mfma_mixed(mem_s + kb * 32, 136, Bs2, a2, wm, wn, lane);
    }
  };
  auto store_tile = [&](bf16* dst) {
#pragma unroll
    for (int c = 0; c < 8; c++) {
      int off = c * 2048 + tid * 8;
      int row = off >> 7, col = off & 127;
      *(uint4*)(dst + (size_t)bm0 * DD + off) = *(uint4*)&mem_s[row * 136 + col];
    }
  };

  if constexpr (LAST == 0) {
    f32x4 acc2[4][4] = {};
    GEMM2(0, acc2);
    // delta = relu(LN(acc2+eub)); ea = LN(ea + delta)
#pragma unroll
    for (int j = 0; j < 4; j++) {
      float bj = eub[colb + j * 16];
#pragma unroll
      for (int i = 0; i < 4; i++)
#pragma unroll
        for (int q = 0; q < 4; q++) acc2[i][j][q] += bj;
    }
    __syncthreads();
    row_ln_stats(acc2, red_s, red_q, wm, wn, lane);
    __syncthreads();
#pragma unroll
    for (int i = 0; i < 4; i++) {
#pragma unroll
      for (int q = 0; q < 4; q++) {
        int row = rowb + i * 16 + q;
        float Sm = red_s[row] + red_s[128 + row];
        float Qs = red_q[row] + red_q[128 + row];
        float mu = Sm * 0.0078125f;
        float var = Qs * 0.0078125f - mu * mu;
        float inv = 1.0f / sqrtf(var + 1e-5f);
        int r = bm0 + row;
#pragma unroll
        for (int j = 0; j < 4; j++) {
          float d = fmaxf((acc2[i][j][q] - mu) * inv, 0.f);
          float eo = __bfloat162float(eah[(size_t)r * DD + colb + j * 16]);
          acc2[i][j][q] = eo + d;
        }
      }
    }
    __syncthreads();
    row_ln_stats(acc2, red_s, red_q, wm, wn, lane);
    __syncthreads();
#pragma unroll
    for (int i = 0; i < 4; i++) {
#pragma unroll
      for (int q = 0; q < 4; q++) {
        int row = rowb + i * 16 + q;
        float Sm = red_s[row] + red_s[128 + row];
        float Qs = red_q[row] + red_q[128 + row];
        float mu = Sm * 0.0078125f;
        float var = Qs * 0.0078125f - mu * mu;
        float inv = 1.0f / sqrtf(var + 1e-5f);
#pragma unroll
        for (int j = 0; j < 4; j++)
          mem_s[row * 136 + colb + j * 16] =
              __float2bfloat16((acc2[i][j][q] - mu) * inv);
      }
    }
    __syncthreads();
    store_tile(eah);
  } else {
    // ---- K = mem @ W_K^T ; logits in-register ----
    f32x4 acc2[4][4] = {};
    GEMM2(0, acc2);
#pragma unroll
    for (int i = 0; i < 4; i++) {
#pragma unroll
      for (int q = 0; q < 4; q++) {
        int row = rowb + i * 16 + q;
        int dst = sdst[row];
#pragma unroll
        for (int j = 0; j < 4; j++) {
          int h = wn * 4 + j;
          float qv = __bfloat162float(qh[(size_t)dst * DD + h * 16 + lr]);
          float p = acc2[i][j][q] * qv;
#pragma unroll
          for (int off = 1; off < 16; off <<= 1) p += __shfl_xor(p, off);
          if (lr == 0) {
            p *= 0.25f;
            int e = bm0 + row;
            logi[(size_t)e * 8 + h] = p;
            unsigned u = __float_as_uint(p);
            u = (u & 0x80000000u) ? ~u : (u | 0x80000000u);
            atomicMax(nmax + (size_t)dst * 8 + h, u);
          }
        }
      }
    }
    // ---- V = mem @ W_V^T ----
    f32x4 acc3[4][4] = {};
    GEMM2(128 * DD, acc3);
    __syncthreads();
#pragma unroll
    for (int i = 0; i < 4; i++)
#pragma unroll
      for (int q = 0; q < 4; q++) {
        int row = rowb + i * 16 + q;
#pragma unroll
        for (int j = 0; j < 4; j++)
          mem_s[row * 136 + colb + j * 16] = __float2bfloat16(acc3[i][j][q]);
      }
    __syncthreads();
    store_tile(vout);
  }
}

// ================= generic GEMM via gload_lds 2-phase =================
// EPI: 1 bf16 staged | 5 bias+relu->bf16 staged | 6 +x1+b2, LN -> f32 staged
template<int EPI>
__global__ __launch_bounds__(256, 3) void k_gemmG(
    const bf16* __restrict__ A, const bf16* __restrict__ B, void* __restrict__ out,
    const float* __restrict__ bias, const float* __restrict__ aux,
    int M, int K, int lda, int ldc)
{
  __shared__ __align__(16) char smem[36864];
  bf16* const stg = (bf16*)smem;                 // [128][136] (aliases stage bufs)
  float* const red_s = (float*)(smem + 34816);
  float* const red_q = (float*)(smem + 35840);

  const int tid = threadIdx.x, lane = tid & 63, w = tid >> 6;
  const int wm = w >> 1, wn = w & 1;
  const int bm0 = blockIdx.x * BM, bn0 = blockIdx.y * BM;
  const int swzE = ((lane & 3) ^ ((lane >> 3) & 3)) * 8;

  const bf16* pA[2];
  const bf16* pB[2];
#pragma unroll
  for (int r = 0; r < 2; r++) {
    int ra = bm0 + r * 64 + w * 16 + (lane >> 2);
    if (ra > M - 1) ra = M - 1;
    pA[r] = A + (size_t)ra * lda + swzE;
    pB[r] = B + (size_t)(bn0 + r * 64 + w * 16 + (lane >> 2)) * K + swzE;
  }
  auto STAGE = [&](int kb, int buf) {
#pragma unroll
    for (int r = 0; r < 2; r++) {
      gload16(pA[r] + kb * 32, smem + buf * 8192 + r * 4096 + w * 1024);
      gload16(pB[r] + kb * 32, smem + 16384 + buf * 8192 + r * 4096 + w * 1024);
    }
  };

  f32x4 acc[4][4] = {};
  const int KB = K >> 5;
  STAGE(0, 0);
  __syncthreads();
  int buf = 0;
#pragma unroll 1
  for (int kb = 0; kb < KB; kb++) {
    if (kb + 1 < KB) STAGE(kb + 1, buf ^ 1);
    mfma_swz((const bf16*)(smem + buf * 8192), (const bf16*)(smem + 16384 + buf * 8192),
             acc, wm, wn, lane);
    __syncthreads();
    buf ^= 1;
  }

  const int lr = lane & 15, lg = lane >> 4;
  const int colb = wn * 64 + lr;
  const int rowb = wm * 64 + lg * 4;

  if constexpr (EPI == 1 || EPI == 5) {
    if constexpr (EPI == 5) {
#pragma unroll
      for (int j = 0; j < 4; j++) {
        float b = bias[bn0 + colb + j * 16];
#pragma unroll
        for (int i = 0; i < 4; i++)
#pragma unroll
          for (int q = 0; q < 4; q++) acc[i][j][q] = fmaxf(acc[i][j][q] + b, 0.f);
      }
    }
#pragma unroll
    for (int i = 0; i < 4; i++)
#pragma unroll
      for (int q = 0; q < 4; q++) {
        int row = rowb + i * 16 + q;
#pragma unroll
        for (int j = 0; j < 4; j++)
          stg[row * 136 + colb + j * 16] = __float2bfloat16(acc[i][j][q]);
      }
    __syncthreads();
#pragma unroll
    for (int c = 0; c < 8; c++) {
      int off = c * 2048 + tid * 8;
      int row = off >> 7, col = off & 127;
      int r = bm0 + row;
      if (r < M)
        *(uint4*)((bf16*)out + (size_t)r * ldc + bn0 + col) = *(uint4*)&stg[row * 136 + col];
    }
  }

  if constexpr (EPI == 6) {
#pragma unroll
    for (int i = 0; i < 4; i++)
#pragma unroll
      for (int q = 0; q < 4; q++) {
        int r = bm0 + rowb + i * 16 + q;
        if (r < M) {
#pragma unroll
          for (int j = 0; j < 4; j++)
            acc[i][j][q] += bias[colb + j * 16] + aux[(size_t)r * DD + colb + j * 16];
        }
      }
    row_ln_stats(acc, red_s, red_q, wm, wn, lane);
    __syncthreads();
    float* const fstg = (float*)smem;   // [64][132] f32
#pragma unroll
    for (int h = 0; h < 2; h++) {
      if (wm == h) {
#pragma unroll
        for (int i = 0; i < 4; i++)
#pragma unroll
          for (int q = 0; q < 4; q++) {
            int row = rowb + i * 16 + q;
            float Sm = red_s[row] + red_s[128 + row];
            float Qs = red_q[row] + red_q[128 + row];
            float mu = Sm * 0.0078125f;
            float var = Qs * 0.0078125f - mu * mu;
            float inv = 1.0f / sqrtf(var + 1e-5f);
            int rloc = row - h * 64;
#pragma unroll
            for (int j = 0; j < 4; j++)
              fstg[rloc * 132 + colb + j * 16] = (acc[i][j][q] - mu) * inv;
          }
      }
      __syncthreads();
#pragma unroll
      for (int c = 0; c < 8; c++) {
        int boff = c * 4096 + tid * 16;
        int row = boff >> 9, col = (boff & 511) >> 2;
        int r = bm0 + h * 64 + row;
        if (r < M)
          *(float4*)((float*)out + (size_t)r * DD + col) = *(float4*)&fstg[row * 132 + col];
      }
      __syncthreads();
    }
  }
}

// ===== msg GEMM (attn-scaled A, reg-staged; evals/nsum normalization folded) + scatter =====
__global__ __launch_bounds__(256) void k_msg(
    const bf16* __restrict__ Vh, const bf16* __restrict__ Wo,
    float* __restrict__ aggr, const float* __restrict__ evals, const float* __restrict__ nsum,
    const int* __restrict__ e0, const int* __restrict__ e1, const int* __restrict__ e2)
{
  __shared__ __align__(16) bf16 As[128 * 40];
  __shared__ __align__(16) bf16 Bs[128 * 40];
  __shared__ int sdst[128];
  const int tid = threadIdx.x, lane = tid & 63, w = tid >> 6, wm = w >> 1, wn = w & 1;
  const int bm0 = blockIdx.x * BM;
  if (tid < 128) sdst[tid] = edge_dst(bm0 + tid, e0, e1, e2);
  __syncthreads();
  f32x4 acc[4][4] = {};
#pragma unroll 1
  for (int kb = 0; kb < 4; kb++) {
    const int k0 = kb * 32;
    for (int c = tid; c < 512; c += 256) {
      int row = c >> 2, c8 = (c & 3) * 8;
      int e = bm0 + row;
      int h = (k0 + c8) >> 4;
      uint4 v = *(const uint4*)(Vh + (size_t)e * DD + k0 + c8);
      float at = evals[(size_t)e * 8 + h] / (nsum[(size_t)sdst[row] * 8 + h] + 1e-16f);
      union { uint4 u; bf16 hh[8]; } vv; vv.u = v;
#pragma unroll
      for (int t = 0; t < 8; t++)
        vv.hh[t] = __float2bfloat16(at * __bfloat162float(vv.hh[t]));
      *(uint4*)&As[row * 40 + c8] = vv.u;
      *(uint4*)&Bs[row * 40 + c8] = *(const uint4*)(Wo + (size_t)row * DD + k0 + c8);
    }
    __syncthreads();
    mfma_step(As, 40, Bs, 40, acc, wm, wn, lane);
    __syncthreads();
  }
  const int lr = lane & 15, lg = lane >> 4;
  const int colb = wn * 64 + lr;
  const int rowb = wm * 64 + lg * 4;
#pragma unroll
  for (int i = 0; i < 4; i++)
#pragma unroll
    for (int q = 0; q < 4; q++) {
      int dst = sdst[rowb + i * 16 + q];
#pragma unroll
      for (int j = 0; j < 4; j++)
        atomicAdd(aggr + (size_t)dst * DD + colb + j * 16, acc[i][j][q]);
    }
}

// ================= small kernels =================
__device__ __forceinline__ float2 ln_pair(float2 v, float eps) {
  float s = v.x + v.y, sq = v.x * v.x + v.y * v.y;
#pragma unroll
  for (int o = 32; o > 0; o >>= 1) {
    s += __shfl_xor(s, o);
    sq += __shfl_xor(sq, o);
  }
  float mu = s * 0.0078125f;
  float var = sq * 0.0078125f - mu * mu;
  float inv = 1.0f / sqrtf(var + eps);
  return make_float2((v.x - mu) * inv, (v.y - mu) * inv);
}

__global__ void k_init_ea(const float* __restrict__ a2a, const float* __restrict__ l2l,
                          const float* __restrict__ rpe, const float* __restrict__ rpeW,
                          const float* __restrict__ rpeb, bf16* __restrict__ eah) {
  int r = blockIdx.x * 4 + (threadIdx.x >> 6);
  int lane = threadIdx.x & 63;
  int ty = r >> 16, idx = r & 65535;
  int c0 = lane * 2;
  float2 y;
  if (ty < 2) {
    y = *(const float2*)((ty == 0 ? a2a : l2l) + (size_t)idx * DD + c0);
  } else {
    float rp0 = rpe[idx * 5 + 0], rp1 = rpe[idx * 5 + 1], rp2 = rpe[idx * 5 + 2];
    float rp3 = rpe[idx * 5 + 3], rp4 = rpe[idx * 5 + 4];
    float2 v;
    v.x = rpeb[c0]     + rp0 * rpeW[c0 * 5]           + rp1 * rpeW[c0 * 5 + 1]
        + rp2 * rpeW[c0 * 5 + 2]     + rp3 * rpeW[c0 * 5 + 3]     + rp4 * rpeW[c0 * 5 + 4];
    v.y = rpeb[c0 + 1] + rp0 * rpeW[(c0 + 1) * 5]     + rp1 * rpeW[(c0 + 1) * 5 + 1]
        + rp2 * rpeW[(c0 + 1) * 5 + 2] + rp3 * rpeW[(c0 + 1) * 5 + 3] + rp4 * rpeW[(c0 + 1) * 5 + 4];
    y = ln_pair(v, 1e-5f);
    y.x = fmaxf(y.x, 0.f);
    y.y = fmaxf(y.y, 0.f);
  }
  size_t o = (size_t)r * DD + c0;
  eah[o] = __float2bfloat16(y.x);
  eah[o + 1] = __float2bfloat16(y.y);
}

__global__ void k_x1(const float* __restrict__ actors, const float* __restrict__ lanesp,
                     const float* __restrict__ aggr, float* __restrict__ x1,
                     bf16* __restrict__ x1h, int R) {
  int r = blockIdx.x * 4 + (threadIdx.x >> 6);
  if (r >= R) return;
  int lane = threadIdx.x & 63;
  int c0 = lane * 2;
  const float* xp = (r < NACT) ? (actors + (size_t)r * DD) : (lanesp + (size_t)(r - NACT) * DD);
  float2 v = *(const float2*)(xp + c0);
  float2 a = *(const float2*)(aggr + (size_t)r * DD + c0);
  v.x += a.x; v.y += a.y;
  float2 y = ln_pair(v, 1e-5f);
  size_t o = (size_t)r * DD + c0;
  *(float2*)(x1 + o) = y;
  x1h[o] = __float2bfloat16(y.x);
  x1h[o + 1] = __float2bfloat16(y.y);
}

__global__ void k_evals(float* __restrict__ logit, const unsigned* __restrict__ nmax,
                        float* __restrict__ nsum,
                        const int* __restrict__ e0, const int* __restrict__ e1,
                        const int* __restrict__ e2) {
  int gid = blockIdx.x * 256 + threadIdx.x;
  int e = gid >> 3, h = gid & 7;
  int dst = edge_dst(e, e0, e1, e2);
  unsigned u = nmax[(size_t)dst * 8 + h];
  float m = (u & 0x80000000u) ? __uint_as_float(u ^ 0x80000000u) : __uint_as_float(~u);
  float v = expf(logit[gid] - m);
  logit[gid] = v;
  atomicAdd(nsum + (size_t)dst * 8 + h, v);
}

__global__ void k_conv(const float* __restrict__ a, bf16* __restrict__ b, int n) {
  int i = blockIdx.x * 256 + threadIdx.x;
  if (i < n) b[i] = __float2bfloat16(a[i]);
}

__global__ void k_x0h(const float* __restrict__ actors, const float* __restrict__ lanesp,
                      bf16* __restrict__ x0h) {
  int gid = blockIdx.x * 256 + threadIdx.x;
  int n = gid >> 7, c = gid & 127;
  float v = (n < NACT) ? actors[(size_t)n * DD + c] : lanesp[(size_t)(n - NACT) * DD + c];
  x0h[gid] = __float2bfloat16(v);
}

// ================= host =================
extern "C" void kernel_launch(void* const* d_in, const int* in_sizes, int n_in,
                              void* d_out, int out_size, void* d_ws, size_t ws_size,
                              hipStream_t stream) {
  (void)in_sizes; (void)n_in; (void)out_size;
  if (ws_size < (128ull << 20)) return;  // tripwire

  const float* actors = (const float*)d_in[0];
  const float* lanesp = (const float*)d_in[1];
  const float* a2a    = (const float*)d_in[2];
  const float* l2l    = (const float*)d_in[3];
  const float* rpe    = (const float*)d_in[4];
  const float* rpeW   = (const float*)d_in[5];
  const float* rpeb   = (const float*)d_in[6];
  const float* mpW    = (const float*)d_in[7];
  const float* mpb    = (const float*)d_in[8];
  const float* euW    = (const float*)d_in[9];
  const float* eub    = (const float*)d_in[10];
  const float* Wq     = (const float*)d_in[11];
  const float* Wk     = (const float*)d_in[12];
  const float* Wv     = (const float*)d_in[13];
  const float* Wo     = (const float*)d_in[14];
  const float* fW1    = (const float*)d_in[15];
  const float* fb1    = (const float*)d_in[16];
  const float* fW2    = (const float*)d_in[17];
  const float* fb2    = (const float*)d_in[18];
  const int* e0 = (const int*)d_in[27];
  const int* e1 = (const int*)d_in[28];
  const int* e2 = (const int*)d_in[29];

  char* ws = (char*)d_ws;
  bf16* W_MP = (bf16*)ws;            // 147456
  bf16* W_EU = W_MP + 147456;        // 32768
  bf16* W_WQ = W_EU + 32768;         // 16384
  bf16* W_KV = W_WQ + 16384;         // 32768 (K rows 0-127, V rows 128-255)
  bf16* W_WO = W_KV + 32768;         // 16384
  bf16* W_F1 = W_WO + 16384;         // 32768
  bf16* W_F2 = W_F1 + 32768;         // 32768

  bf16*  X0H = (bf16*)(ws + (1ull << 20));    // NN*128 bf16 (later X1H)
  bf16*  QH  = (bf16*)(ws + (12ull << 20));   // NN*128 bf16
  float* POOL = (float*)(ws + (24ull << 20));
  float*    AGGR = POOL;                      // NN*128 f32
  float*    X1   = POOL + 5120000;            // NN*128 f32
  float*    LOGI = POOL + 10240000;           // EE*8 f32 (raw -> exp)
  unsigned* NMAX = (unsigned*)(POOL + 11812864);  // NN*8
  float*    NSUM = POOL + 12132864;           // NN*8
  bf16* EAH = (bf16*)(ws + (80ull << 20));    // EE*128 bf16
  bf16* VH  = EAH;                            // V aliases EAH (per-row overwrite, safe)
  bf16* X1H = X0H;
  bf16* H1H = EAH;                            // FFN hidden reuses EAH after msg GEMM

  k_conv<<<576, 256, 0, stream>>>(mpW, W_MP, 147456);
  k_conv<<<128, 256, 0, stream>>>(euW, W_EU, 32768);
  k_conv<<<64, 256, 0, stream>>>(Wq + 2 * 16384, W_WQ, 16384);
  k_conv<<<64, 256, 0, stream>>>(Wk + 2 * 16384, W_KV, 16384);
  k_conv<<<64, 256, 0, stream>>>(Wv + 2 * 16384, W_KV + 16384, 16384);
  k_conv<<<64, 256, 0, stream>>>(Wo + 2 * 16384, W_WO, 16384);
  k_conv<<<128, 256, 0, stream>>>(fW1 + 2 * 32768, W_F1, 32768);
  k_conv<<<128, 256, 0, stream>>>(fW2 + 2 * 32768, W_F2, 32768);
  k_x0h<<<20000, 256, 0, stream>>>(actors, lanesp, X0H);
  k_init_ea<<<49152, 256, 0, stream>>>(a2a, l2l, rpe, rpeW, rpeb, EAH);

  // Q = x0 @ Wq^T (bf16), needed by layer-2 logits
  k_gemmG<1><<<313, 256, 0, stream>>>(X0H, W_WQ, QH, nullptr, nullptr, NN, 128, 128, DD);

  hipMemsetAsync(AGGR, 0, (size_t)NN * DD * 4, stream);
  hipMemsetAsync(NMAX, 0, (size_t)NN * 8 * 4, stream);
  hipMemsetAsync(NSUM, 0, (size_t)NN * 8 * 4, stream);

  // layers 0,1: fused edge-attr evolution (node state resets to token0 via DDC)
  for (int i = 0; i < 2; i++) {
    k_fused<0><<<EE / BM, 256, 0, stream>>>(W_MP + i * 49152, W_EU + i * 16384,
        mpb + i * 128, eub + i * 128, EAH, X0H, nullptr, nullptr,
        nullptr, nullptr, e0, e1, e2);
  }
  // layer 2: fused cat->mem->{K->logits, V}
  k_fused<1><<<EE / BM, 256, 0, stream>>>(W_MP + 2 * 49152, W_KV,
      mpb + 2 * 128, nullptr, EAH, X0H, QH, VH, LOGI, NMAX, e0, e1, e2);

  k_evals<<<EE * 8 / 256, 256, 0, stream>>>(LOGI, NMAX, NSUM, e0, e1, e2);

  // msg = (attn*V) @ Wo^T, scatter-add into AGGR (attn normalization folded in)
  k_msg<<<EE / BM, 256, 0, stream>>>(VH, W_WO, AGGR, LOGI, NSUM, e0, e1, e2);

  k_x1<<<NN / 4, 256, 0, stream>>>(actors, lanesp, AGGR, X1, X1H, NN);
  k_gemmG<5><<<dim3(313, 2), 256, 0, stream>>>(X1H, W_F1, H1H, fb1 + 2 * 256, nullptr,
                                               NN, 128, 128, 256);
  k_gemmG<6><<<dim3(313, 1), 256, 0, stream>>>(H1H, W_F2, d_out, fb2 + 2 * 128, X1,
                                               NN, 256, 256, DD);
}